// Round 13
// baseline (672.005 us; speedup 1.0000x reference)
//
#include <hip/hip_runtime.h>
#include <cstdint>

typedef unsigned short u16;
typedef __attribute__((ext_vector_type(8))) short short8;   // 8 bf16 (MFMA A/B frag)
typedef __attribute__((ext_vector_type(4))) float floatx4;  // MFMA C/D frag

__device__ __forceinline__ float b2f(u16 u) {
    union { unsigned int i; float f; } c; c.i = ((unsigned int)u) << 16; return c.f;
}
__device__ __forceinline__ u16 f2b(float f) {
    union { float f; unsigned int i; } c; c.f = f;
    unsigned int u = c.i;
    u = u + 0x7FFFu + ((u >> 16) & 1u);   // RNE
    return (u16)(u >> 16);
}
__device__ __forceinline__ float rdlane(float v, int l) {
    union { float f; int i; } c; c.f = v;
    union { int i; float f; } o; o.i = __builtin_amdgcn_readlane(c.i, l);
    return o.f;
}

// ---------------------------------------------------------------------------
// Fused Q/K/V projection GEMM. Y[m,n] = sum_k x[m,k]*W[n,k] + bias[n].
// grid (32, 24): which = blockIdx.y>>3 (0=q fp32, 1=k bf16, 2=v fp32).
// ---------------------------------------------------------------------------
__global__ __launch_bounds__(256) void gemm_qkv(
    const float* __restrict__ x,
    const float* __restrict__ Wq, const float* __restrict__ Wk, const float* __restrict__ Wv,
    const float* __restrict__ bq, const float* __restrict__ bk, const float* __restrict__ bv,
    float* __restrict__ qout, u16* __restrict__ kout, float* __restrict__ vout)
{
    __shared__ u16 xs[64 * 72];
    __shared__ u16 wsl[64 * 72];
    int tid = threadIdx.x;
    int lane = tid & 63;
    int wv = tid >> 6;
    int lo = lane & 15, hi = lane >> 4;
    int which = blockIdx.y >> 3;
    int m0 = blockIdx.x * 64, n0 = (blockIdx.y & 7) * 64;
    const float* W    = which == 0 ? Wq : (which == 1 ? Wk : Wv);
    const float* bias = which == 0 ? bq : (which == 1 ? bk : bv);

    floatx4 acc[4];
#pragma unroll
    for (int mt = 0; mt < 4; ++mt) acc[mt] = (floatx4){0.f, 0.f, 0.f, 0.f};

    for (int k0 = 0; k0 < 512; k0 += 64) {
        __syncthreads();
#pragma unroll
        for (int i = 0; i < 2; ++i) {
            int v = tid + i * 256;
            int row = v >> 3, c8 = (v & 7) * 8;
            const float* ap = x + (m0 + row) * 512 + k0 + c8;
            const float* wp = W + (n0 + row) * 512 + k0 + c8;
            float4 a0 = *(const float4*)(ap);
            float4 a1 = *(const float4*)(ap + 4);
            float4 w0 = *(const float4*)(wp);
            float4 w1v = *(const float4*)(wp + 4);
            union { u16 u[8]; uint4 q; } ca, cw;
            ca.u[0] = f2b(a0.x); ca.u[1] = f2b(a0.y); ca.u[2] = f2b(a0.z); ca.u[3] = f2b(a0.w);
            ca.u[4] = f2b(a1.x); ca.u[5] = f2b(a1.y); ca.u[6] = f2b(a1.z); ca.u[7] = f2b(a1.w);
            cw.u[0] = f2b(w0.x); cw.u[1] = f2b(w0.y); cw.u[2] = f2b(w0.z); cw.u[3] = f2b(w0.w);
            cw.u[4] = f2b(w1v.x); cw.u[5] = f2b(w1v.y); cw.u[6] = f2b(w1v.z); cw.u[7] = f2b(w1v.w);
            *(uint4*)(xs + row * 72 + c8)  = ca.q;
            *(uint4*)(wsl + row * 72 + c8) = cw.q;
        }
        __syncthreads();
#pragma unroll
        for (int ks = 0; ks < 2; ++ks) {
            short8 bfr = *(const short8*)(wsl + (wv * 16 + lo) * 72 + ks * 32 + hi * 8);
#pragma unroll
            for (int mt = 0; mt < 4; ++mt) {
                short8 afr = *(const short8*)(xs + (mt * 16 + lo) * 72 + ks * 32 + hi * 8);
                acc[mt] = __builtin_amdgcn_mfma_f32_16x16x32_bf16(afr, bfr, acc[mt], 0, 0, 0);
            }
        }
    }

    int n = n0 + wv * 16 + lo;
    float bv2 = bias[n];
    int h = n >> 6, dd = n & 63;
#pragma unroll
    for (int mt = 0; mt < 4; ++mt) {
#pragma unroll
        for (int r = 0; r < 4; ++r) {
            int m = m0 + mt * 16 + hi * 4 + r;      // C/D: row=(lane>>4)*4+reg, col=lane&15
            float y = acc[mt][r] + bv2;
            int b = m >> 10, c = m & 1023;
            int idx = (((b * 8 + h) * 1024) + c) * 64 + dd;
            if (which == 0)      qout[idx] = y;
            else if (which == 1) kout[idx] = f2b(y);
            else                 vout[idx] = y;
        }
    }
}

// ---------------------------------------------------------------------------
// Output GEMM: Y[m,n] = sum_k A[m,k]*Wo[n,k] + bo[n], fp32 out, [m*512+n].
// ---------------------------------------------------------------------------
__global__ __launch_bounds__(256) void gemm_out(
    const float* __restrict__ A, const float* __restrict__ W, const float* __restrict__ bias,
    float* __restrict__ outf)
{
    __shared__ u16 xs[64 * 72];
    __shared__ u16 wsl[64 * 72];
    int tid = threadIdx.x;
    int lane = tid & 63;
    int wv = tid >> 6;
    int lo = lane & 15, hi = lane >> 4;
    int m0 = blockIdx.x * 64, n0 = blockIdx.y * 64;

    floatx4 acc[4];
#pragma unroll
    for (int mt = 0; mt < 4; ++mt) acc[mt] = (floatx4){0.f, 0.f, 0.f, 0.f};

    for (int k0 = 0; k0 < 512; k0 += 64) {
        __syncthreads();
#pragma unroll
        for (int i = 0; i < 2; ++i) {
            int v = tid + i * 256;
            int row = v >> 3, c8 = (v & 7) * 8;
            const float* ap = A + (m0 + row) * 512 + k0 + c8;
            const float* wp = W + (n0 + row) * 512 + k0 + c8;
            float4 a0 = *(const float4*)(ap);
            float4 a1 = *(const float4*)(ap + 4);
            float4 w0 = *(const float4*)(wp);
            float4 w1v = *(const float4*)(wp + 4);
            union { u16 u[8]; uint4 q; } ca, cw;
            ca.u[0] = f2b(a0.x); ca.u[1] = f2b(a0.y); ca.u[2] = f2b(a0.z); ca.u[3] = f2b(a0.w);
            ca.u[4] = f2b(a1.x); ca.u[5] = f2b(a1.y); ca.u[6] = f2b(a1.z); ca.u[7] = f2b(a1.w);
            cw.u[0] = f2b(w0.x); cw.u[1] = f2b(w0.y); cw.u[2] = f2b(w0.z); cw.u[3] = f2b(w0.w);
            cw.u[4] = f2b(w1v.x); cw.u[5] = f2b(w1v.y); cw.u[6] = f2b(w1v.z); cw.u[7] = f2b(w1v.w);
            *(uint4*)(xs + row * 72 + c8)  = ca.q;
            *(uint4*)(wsl + row * 72 + c8) = cw.q;
        }
        __syncthreads();
#pragma unroll
        for (int ks = 0; ks < 2; ++ks) {
            short8 bfr = *(const short8*)(wsl + (wv * 16 + lo) * 72 + ks * 32 + hi * 8);
#pragma unroll
            for (int mt = 0; mt < 4; ++mt) {
                short8 afr = *(const short8*)(xs + (mt * 16 + lo) * 72 + ks * 32 + hi * 8);
                acc[mt] = __builtin_amdgcn_mfma_f32_16x16x32_bf16(afr, bfr, acc[mt], 0, 0, 0);
            }
        }
    }

    int n = n0 + wv * 16 + lo;
    float bv = bias[n];
#pragma unroll
    for (int mt = 0; mt < 4; ++mt)
#pragma unroll
        for (int r = 0; r < 4; ++r) {
            int m = m0 + mt * 16 + hi * 4 + r;
            outf[m * 512 + n] = acc[mt][r] + bv;
        }
}

// ---------------------------------------------------------------------------
// Fused second-order attention, v9 = v8 at 16-key inner tiles (spill fix):
// acc[4] (16 regs) + bf/bfn[2] (8+8) instead of acc[4][2]+bf/bfn[2][2]
// -> ~110 live regs < 128 budget -> 4 waves/SIMD WITHOUT scratch spills.
// Op count per 32 keys is identical to v8 (same MFMA/exp2/shuffle/readlane).
// ---------------------------------------------------------------------------
__global__ __launch_bounds__(256, 4) void attn9(
    const float* __restrict__ qf, const u16* __restrict__ kb, const float* __restrict__ vf,
    const float* __restrict__ w1, const float* __restrict__ b1, const float* __restrict__ w2,
    float* __restrict__ ao)
{
    __shared__ float q_l[4 * 64];
    int tid = threadIdx.x;
    int lane = tid & 63;
    int wv = tid >> 6;
    int lo = lane & 15, hi = lane >> 4;
    int bh = blockIdx.x >> 8;                      // 0..15 = b*8+h
    int qi = ((blockIdx.x & 255) << 2) | wv;       // query 0..1023

    q_l[wv * 64 + lane] = qf[(bh * 1024 + qi) * 64 + lane];

    // qp[e]+b1[e] at lane=e
    float qpacc = b1[lane];
#pragma unroll
    for (int d8 = 0; d8 < 64; d8 += 8) {
        float4 wa = *(const float4*)(w1 + lane * 192 + d8);
        float4 wb = *(const float4*)(w1 + lane * 192 + d8 + 4);
        const float* q8 = q_l + wv * 64 + d8;      // wave-uniform broadcast reads
        qpacc = __builtin_fmaf(q8[0], wa.x, qpacc);
        qpacc = __builtin_fmaf(q8[1], wa.y, qpacc);
        qpacc = __builtin_fmaf(q8[2], wa.z, qpacc);
        qpacc = __builtin_fmaf(q8[3], wa.w, qpacc);
        qpacc = __builtin_fmaf(q8[4], wb.x, qpacc);
        qpacc = __builtin_fmaf(q8[5], wb.y, qpacc);
        qpacc = __builtin_fmaf(q8[6], wb.z, qpacc);
        qpacc = __builtin_fmaf(q8[7], wb.w, qpacc);
    }
    // rearrange to C/D-row indexing: e = mt*16 + hi*4 + r
    float qpb[4][4], w2c[4][4];
    float w2row = w2[lane] * 0.18033688f;          // w2[e] * (1/8) * log2(e)
#pragma unroll
    for (int mt = 0; mt < 4; ++mt)
#pragma unroll
        for (int r = 0; r < 4; ++r) {
            int e = mt * 16 + hi * 4 + r;
            qpb[mt][r] = __shfl(qpacc, e);
            w2c[mt][r] = __shfl(w2row, e);
        }

    // q pieces for frag build: qv2[ks][j] = q[ks*32 + hi*8 + j]
    float qv2[2][8];
#pragma unroll
    for (int ks = 0; ks < 2; ++ks)
#pragma unroll
        for (int j = 0; j < 8; ++j)
            qv2[ks][j] = q_l[wv * 64 + ks * 32 + hi * 8 + j];

    // A-frags: qw'[e = mt*16+lo][dd = ks*32 + hi*8 + j], bf16
    short8 af[4][2];
#pragma unroll
    for (int mt = 0; mt < 4; ++mt) {
        const float* wr = w1 + (mt * 16 + lo) * 192;
#pragma unroll
        for (int ks = 0; ks < 2; ++ks) {
            int dd0 = ks * 32 + hi * 8;
            float4 a0 = *(const float4*)(wr + 128 + dd0);
            float4 a1 = *(const float4*)(wr + 128 + dd0 + 4);
            float4 k0 = *(const float4*)(wr + 64 + dd0);
            float4 k1 = *(const float4*)(wr + 64 + dd0 + 4);
            union { u16 u[8]; short8 s; } cv;
            cv.u[0] = f2b(__builtin_fmaf(qv2[ks][0], a0.x, k0.x));
            cv.u[1] = f2b(__builtin_fmaf(qv2[ks][1], a0.y, k0.y));
            cv.u[2] = f2b(__builtin_fmaf(qv2[ks][2], a0.z, k0.z));
            cv.u[3] = f2b(__builtin_fmaf(qv2[ks][3], a0.w, k0.w));
            cv.u[4] = f2b(__builtin_fmaf(qv2[ks][4], a1.x, k1.x));
            cv.u[5] = f2b(__builtin_fmaf(qv2[ks][5], a1.y, k1.y));
            cv.u[6] = f2b(__builtin_fmaf(qv2[ks][6], a1.z, k1.z));
            cv.u[7] = f2b(__builtin_fmaf(qv2[ks][7], a1.w, k1.w));
            af[mt][ks] = cv.s;
        }
    }

    float l_run = 0.f;
    float oa0 = 0.f, oa1 = 0.f, oa2 = 0.f, oa3 = 0.f;
    const u16*   kbase = kb + bh * 65536;
    const float* vbase = vf + bh * 65536;
    const floatx4 z = (floatx4){0.f, 0.f, 0.f, 0.f};

    // prologue: load B-frags for js = 0 (16 keys, j = lo)
    short8 bf[2];
#pragma unroll
    for (int ks = 0; ks < 2; ++ks) {
        uint4 kv = *(const uint4*)(kbase + lo * 64 + ks * 32 + hi * 8);
        bf[ks] = *(short8*)&kv;
    }

    for (int js = 0; js < 1024; js += 16) {
        // prefetch next 16-key B-frags (latency overlapped with body below)
        int jn = (js + 16) & 1023;                 // last prefetch wraps, unused
        short8 bfn[2];
#pragma unroll
        for (int ks = 0; ks < 2; ++ks) {
            uint4 kv = *(const uint4*)(kbase + (jn + lo) * 64 + ks * 32 + hi * 8);
            bfn[ks] = *(short8*)&kv;
        }

        floatx4 acc[4];
#pragma unroll
        for (int mt = 0; mt < 4; ++mt)
            acc[mt] = __builtin_amdgcn_mfma_f32_16x16x32_bf16(af[mt][0], bf[0], z, 0, 0, 0);
#pragma unroll
        for (int mt = 0; mt < 4; ++mt)
            acc[mt] = __builtin_amdgcn_mfma_f32_16x16x32_bf16(af[mt][1], bf[1], acc[mt], 0, 0, 0);

        // score[j]: sigmoid-gelu (HW exp2) + pair-merged rcp; split chains
        float sa = 0.f, sb = 0.f;
#pragma unroll
        for (int mt = 0; mt < 4; ++mt)
#pragma unroll
            for (int r = 0; r < 4; r += 2) {
                float x0 = acc[mt][r] + qpb[mt][r];
                float x1 = acc[mt][r + 1] + qpb[mt][r + 1];
                float e0 = __builtin_amdgcn_exp2f(x0 * -2.45546696f);
                float e1 = __builtin_amdgcn_exp2f(x1 * -2.45546696f);
                float a0 = 1.0f + e0;
                float a1 = 1.0f + e1;
                float rc = __builtin_amdgcn_rcpf(a0 * a1);
                sa = __builtin_fmaf(x0 * w2c[mt][r], rc * a1, sa);
                sb = __builtin_fmaf(x1 * w2c[mt][r + 1], rc * a0, sb);
            }
        float s = sa + sb;
        s += __shfl_xor(s, 16); s += __shfl_xor(s, 32);   // full e-sum; s[j=lo]

        // fixed-shift softmax numerator (scores bounded |s|<~110, safe)
        float p = __builtin_amdgcn_exp2f(s - 16.0f);
        l_run += p;                                // per-lane partial (over lo)

        // PV: p[j=lane&15] -> v_readlane broadcast, SGPR fma
        const float* vrow = vbase + js * 64 + lane;
#pragma unroll
        for (int j = 0; j < 16; j += 4) {
            float pj0 = rdlane(p, j + 0);
            float pj1 = rdlane(p, j + 1);
            float pj2 = rdlane(p, j + 2);
            float pj3 = rdlane(p, j + 3);
            oa0 = __builtin_fmaf(pj0, vrow[(j + 0) * 64], oa0);
            oa1 = __builtin_fmaf(pj1, vrow[(j + 1) * 64], oa1);
            oa2 = __builtin_fmaf(pj2, vrow[(j + 2) * 64], oa2);
            oa3 = __builtin_fmaf(pj3, vrow[(j + 3) * 64], oa3);
        }

        // rotate pipeline
        bf[0] = bfn[0];
        bf[1] = bfn[1];
    }

    float l = l_run;
    l += __shfl_xor(l, 1); l += __shfl_xor(l, 2);
    l += __shfl_xor(l, 4); l += __shfl_xor(l, 8);
    float outv = (oa0 + oa1 + oa2 + oa3) * __builtin_amdgcn_rcpf(l);
    int b = bh >> 3, h = bh & 7;
    ao[(b * 1024 + qi) * 512 + h * 64 + lane] = outv;   // (B,C,D) fp32
}

// ---------------------------------------------------------------------------
extern "C" void kernel_launch(void* const* d_in, const int* in_sizes, int n_in,
                              void* d_out, int out_size, void* d_ws, size_t ws_size,
                              hipStream_t stream)
{
    (void)in_sizes; (void)n_in; (void)out_size; (void)ws_size;
    const float* x  = (const float*)d_in[0];
    const float* Wq = (const float*)d_in[1];
    const float* bq = (const float*)d_in[2];
    const float* Wk = (const float*)d_in[3];
    const float* bk = (const float*)d_in[4];
    const float* Wv = (const float*)d_in[5];
    const float* bv = (const float*)d_in[6];
    const float* w1 = (const float*)d_in[7];
    const float* b1 = (const float*)d_in[8];
    const float* w2 = (const float*)d_in[9];
    // d_in[10] = b2: scalar shift of all scores -> softmax-invariant -> unused
    const float* Wo = (const float*)d_in[11];
    const float* bo = (const float*)d_in[12];

    char* ws = (char*)d_ws;
    float* q_ws = (float*)(ws);               // 4 MB fp32 (b,h,c,d)
    u16*   k_ws = (u16*)(ws + (4u << 20));    // 2 MB bf16 (b,h,c,d)
    float* v_ws = (float*)(ws + (6u << 20));  // 4 MB fp32 (b,h,c,d)
    float* a_ws = (float*)(ws + (10u << 20)); // 4 MB fp32 (b,c,D)

    dim3 blk(256);
    hipLaunchKernelGGL(gemm_qkv, dim3(32, 24), blk, 0, stream,
                       x, Wq, Wk, Wv, bq, bk, bv, q_ws, k_ws, v_ws);
    hipLaunchKernelGGL(attn9, dim3(4096), blk, 0, stream, q_ws, k_ws, v_ws, w1, b1, w2, a_ws);
    hipLaunchKernelGGL(gemm_out, dim3(32, 8), blk, 0, stream, a_ws, Wo, bo, (float*)d_out);
}

// Round 14
// 575.351 us; speedup vs baseline: 1.1680x; 1.1680x over previous
//
#include <hip/hip_runtime.h>
#include <cstdint>

typedef unsigned short u16;
typedef unsigned int u32;
typedef __attribute__((ext_vector_type(8))) short short8;   // 8 bf16 (MFMA A/B frag)
typedef __attribute__((ext_vector_type(4))) float floatx4;  // MFMA C/D frag

__device__ __forceinline__ float b2f(u16 u) {
    union { unsigned int i; float f; } c; c.i = ((unsigned int)u) << 16; return c.f;
}
__device__ __forceinline__ u16 f2b(float f) {
    union { float f; unsigned int i; } c; c.f = f;
    unsigned int u = c.i;
    u = u + 0x7FFFu + ((u >> 16) & 1u);   // RNE
    return (u16)(u >> 16);
}
__device__ __forceinline__ float rdlane(float v, int l) {
    union { float f; int i; } c; c.f = v;
    union { int i; float f; } o; o.i = __builtin_amdgcn_readlane(c.i, l);
    return o.f;
}
__device__ __forceinline__ float u2f(u32 u) { union { u32 u; float f; } c; c.u = u; return c.f; }

// ---------------------------------------------------------------------------
// Fused Q/K/V projection GEMM. Y[m,n] = sum_k x[m,k]*W[n,k] + bias[n].
// grid (32, 24): which = blockIdx.y>>3 (0=q fp32, 1=k bf16, 2=v fp32).
// ---------------------------------------------------------------------------
__global__ __launch_bounds__(256) void gemm_qkv(
    const float* __restrict__ x,
    const float* __restrict__ Wq, const float* __restrict__ Wk, const float* __restrict__ Wv,
    const float* __restrict__ bq, const float* __restrict__ bk, const float* __restrict__ bv,
    float* __restrict__ qout, u16* __restrict__ kout, float* __restrict__ vout)
{
    __shared__ u16 xs[64 * 72];
    __shared__ u16 wsl[64 * 72];
    int tid = threadIdx.x;
    int lane = tid & 63;
    int wv = tid >> 6;
    int lo = lane & 15, hi = lane >> 4;
    int which = blockIdx.y >> 3;
    int m0 = blockIdx.x * 64, n0 = (blockIdx.y & 7) * 64;
    const float* W    = which == 0 ? Wq : (which == 1 ? Wk : Wv);
    const float* bias = which == 0 ? bq : (which == 1 ? bk : bv);

    floatx4 acc[4];
#pragma unroll
    for (int mt = 0; mt < 4; ++mt) acc[mt] = (floatx4){0.f, 0.f, 0.f, 0.f};

    for (int k0 = 0; k0 < 512; k0 += 64) {
        __syncthreads();
#pragma unroll
        for (int i = 0; i < 2; ++i) {
            int v = tid + i * 256;
            int row = v >> 3, c8 = (v & 7) * 8;
            const float* ap = x + (m0 + row) * 512 + k0 + c8;
            const float* wp = W + (n0 + row) * 512 + k0 + c8;
            float4 a0 = *(const float4*)(ap);
            float4 a1 = *(const float4*)(ap + 4);
            float4 w0 = *(const float4*)(wp);
            float4 w1v = *(const float4*)(wp + 4);
            union { u16 u[8]; uint4 q; } ca, cw;
            ca.u[0] = f2b(a0.x); ca.u[1] = f2b(a0.y); ca.u[2] = f2b(a0.z); ca.u[3] = f2b(a0.w);
            ca.u[4] = f2b(a1.x); ca.u[5] = f2b(a1.y); ca.u[6] = f2b(a1.z); ca.u[7] = f2b(a1.w);
            cw.u[0] = f2b(w0.x); cw.u[1] = f2b(w0.y); cw.u[2] = f2b(w0.z); cw.u[3] = f2b(w0.w);
            cw.u[4] = f2b(w1v.x); cw.u[5] = f2b(w1v.y); cw.u[6] = f2b(w1v.z); cw.u[7] = f2b(w1v.w);
            *(uint4*)(xs + row * 72 + c8)  = ca.q;
            *(uint4*)(wsl + row * 72 + c8) = cw.q;
        }
        __syncthreads();
#pragma unroll
        for (int ks = 0; ks < 2; ++ks) {
            short8 bfr = *(const short8*)(wsl + (wv * 16 + lo) * 72 + ks * 32 + hi * 8);
#pragma unroll
            for (int mt = 0; mt < 4; ++mt) {
                short8 afr = *(const short8*)(xs + (mt * 16 + lo) * 72 + ks * 32 + hi * 8);
                acc[mt] = __builtin_amdgcn_mfma_f32_16x16x32_bf16(afr, bfr, acc[mt], 0, 0, 0);
            }
        }
    }

    int n = n0 + wv * 16 + lo;
    float bv2 = bias[n];
    int h = n >> 6, dd = n & 63;
#pragma unroll
    for (int mt = 0; mt < 4; ++mt) {
#pragma unroll
        for (int r = 0; r < 4; ++r) {
            int m = m0 + mt * 16 + hi * 4 + r;      // C/D: row=(lane>>4)*4+reg, col=lane&15
            float y = acc[mt][r] + bv2;
            int b = m >> 10, c = m & 1023;
            int idx = (((b * 8 + h) * 1024) + c) * 64 + dd;
            if (which == 0)      qout[idx] = y;
            else if (which == 1) kout[idx] = f2b(y);
            else                 vout[idx] = y;
        }
    }
}

// ---------------------------------------------------------------------------
// Output GEMM: Y[m,n] = sum_k A[m,k]*Wo[n,k] + bo[n], fp32 out, [m*512+n].
// ---------------------------------------------------------------------------
__global__ __launch_bounds__(256) void gemm_out(
    const float* __restrict__ A, const float* __restrict__ W, const float* __restrict__ bias,
    float* __restrict__ outf)
{
    __shared__ u16 xs[64 * 72];
    __shared__ u16 wsl[64 * 72];
    int tid = threadIdx.x;
    int lane = tid & 63;
    int wv = tid >> 6;
    int lo = lane & 15, hi = lane >> 4;
    int m0 = blockIdx.x * 64, n0 = blockIdx.y * 64;

    floatx4 acc[4];
#pragma unroll
    for (int mt = 0; mt < 4; ++mt) acc[mt] = (floatx4){0.f, 0.f, 0.f, 0.f};

    for (int k0 = 0; k0 < 512; k0 += 64) {
        __syncthreads();
#pragma unroll
        for (int i = 0; i < 2; ++i) {
            int v = tid + i * 256;
            int row = v >> 3, c8 = (v & 7) * 8;
            const float* ap = A + (m0 + row) * 512 + k0 + c8;
            const float* wp = W + (n0 + row) * 512 + k0 + c8;
            float4 a0 = *(const float4*)(ap);
            float4 a1 = *(const float4*)(ap + 4);
            float4 w0 = *(const float4*)(wp);
            float4 w1v = *(const float4*)(wp + 4);
            union { u16 u[8]; uint4 q; } ca, cw;
            ca.u[0] = f2b(a0.x); ca.u[1] = f2b(a0.y); ca.u[2] = f2b(a0.z); ca.u[3] = f2b(a0.w);
            ca.u[4] = f2b(a1.x); ca.u[5] = f2b(a1.y); ca.u[6] = f2b(a1.z); ca.u[7] = f2b(a1.w);
            cw.u[0] = f2b(w0.x); cw.u[1] = f2b(w0.y); cw.u[2] = f2b(w0.z); cw.u[3] = f2b(w0.w);
            cw.u[4] = f2b(w1v.x); cw.u[5] = f2b(w1v.y); cw.u[6] = f2b(w1v.z); cw.u[7] = f2b(w1v.w);
            *(uint4*)(xs + row * 72 + c8)  = ca.q;
            *(uint4*)(wsl + row * 72 + c8) = cw.q;
        }
        __syncthreads();
#pragma unroll
        for (int ks = 0; ks < 2; ++ks) {
            short8 bfr = *(const short8*)(wsl + (wv * 16 + lo) * 72 + ks * 32 + hi * 8);
#pragma unroll
            for (int mt = 0; mt < 4; ++mt) {
                short8 afr = *(const short8*)(xs + (mt * 16 + lo) * 72 + ks * 32 + hi * 8);
                acc[mt] = __builtin_amdgcn_mfma_f32_16x16x32_bf16(afr, bfr, acc[mt], 0, 0, 0);
            }
        }
    }

    int n = n0 + wv * 16 + lo;
    float bv = bias[n];
#pragma unroll
    for (int mt = 0; mt < 4; ++mt)
#pragma unroll
        for (int r = 0; r < 4; ++r) {
            int m = m0 + mt * 16 + hi * 4 + r;
            outf[m * 512 + n] = acc[mt][r] + bv;
        }
}

// ---------------------------------------------------------------------------
// Fused second-order attention, v10 = v8 (32-key tiles, 4 waves/SIMD) with
// the arch-VGPR side squeezed under 64 to kill scratch spills:
//  * no bfn double-buffer: bf reloaded IN PLACE right after its last MFMA
//    use -> the load gets the whole score+PV segment (~500cy) of slack.
//  * qpb+w2c packed as bf16 pairs in 16 u32 regs (qpb = high half, 1 v_and;
//    w2c = low half, 1 v_lshl). bf16 qp validated in R11 (absmax 6.1e-4).
// AGPR side: af 32 + acc 32 = 64. Arch side: bf 16 + pack 16 + oa/temps ~24.
// ---------------------------------------------------------------------------
__global__ __launch_bounds__(256, 4) void attn10(
    const float* __restrict__ qf, const u16* __restrict__ kb, const float* __restrict__ vf,
    const float* __restrict__ w1, const float* __restrict__ b1, const float* __restrict__ w2,
    float* __restrict__ ao)
{
    __shared__ float q_l[4 * 64];
    int tid = threadIdx.x;
    int lane = tid & 63;
    int wv = tid >> 6;
    int lo = lane & 15, hi = lane >> 4;
    int bh = blockIdx.x >> 8;                      // 0..15 = b*8+h
    int qi = ((blockIdx.x & 255) << 2) | wv;       // query 0..1023

    q_l[wv * 64 + lane] = qf[(bh * 1024 + qi) * 64 + lane];

    // qp[e]+b1[e] at lane=e
    float qpacc = b1[lane];
#pragma unroll
    for (int d8 = 0; d8 < 64; d8 += 8) {
        float4 wa = *(const float4*)(w1 + lane * 192 + d8);
        float4 wb = *(const float4*)(w1 + lane * 192 + d8 + 4);
        const float* q8 = q_l + wv * 64 + d8;      // wave-uniform broadcast reads
        qpacc = __builtin_fmaf(q8[0], wa.x, qpacc);
        qpacc = __builtin_fmaf(q8[1], wa.y, qpacc);
        qpacc = __builtin_fmaf(q8[2], wa.z, qpacc);
        qpacc = __builtin_fmaf(q8[3], wa.w, qpacc);
        qpacc = __builtin_fmaf(q8[4], wb.x, qpacc);
        qpacc = __builtin_fmaf(q8[5], wb.y, qpacc);
        qpacc = __builtin_fmaf(q8[6], wb.z, qpacc);
        qpacc = __builtin_fmaf(q8[7], wb.w, qpacc);
    }
    // packed (qpb | w2c) at C/D-row indexing: e = mt*16 + hi*4 + r
    u32 qw2[4][4];
    float w2row = w2[lane] * 0.18033688f;          // w2[e] * (1/8) * log2(e)
#pragma unroll
    for (int mt = 0; mt < 4; ++mt)
#pragma unroll
        for (int r = 0; r < 4; ++r) {
            int e = mt * 16 + hi * 4 + r;
            u32 qp_b = (u32)f2b(__shfl(qpacc, e));
            u32 wc_b = (u32)f2b(__shfl(w2row, e));
            qw2[mt][r] = (qp_b << 16) | wc_b;
        }

    // q pieces for frag build: qv2[ks][j] = q[ks*32 + hi*8 + j]
    float qv2[2][8];
#pragma unroll
    for (int ks = 0; ks < 2; ++ks)
#pragma unroll
        for (int j = 0; j < 8; ++j)
            qv2[ks][j] = q_l[wv * 64 + ks * 32 + hi * 8 + j];

    // A-frags: qw'[e = mt*16+lo][dd = ks*32 + hi*8 + j], bf16
    short8 af[4][2];
#pragma unroll
    for (int mt = 0; mt < 4; ++mt) {
        const float* wr = w1 + (mt * 16 + lo) * 192;
#pragma unroll
        for (int ks = 0; ks < 2; ++ks) {
            int dd0 = ks * 32 + hi * 8;
            float4 a0 = *(const float4*)(wr + 128 + dd0);
            float4 a1 = *(const float4*)(wr + 128 + dd0 + 4);
            float4 k0 = *(const float4*)(wr + 64 + dd0);
            float4 k1 = *(const float4*)(wr + 64 + dd0 + 4);
            union { u16 u[8]; short8 s; } cv;
            cv.u[0] = f2b(__builtin_fmaf(qv2[ks][0], a0.x, k0.x));
            cv.u[1] = f2b(__builtin_fmaf(qv2[ks][1], a0.y, k0.y));
            cv.u[2] = f2b(__builtin_fmaf(qv2[ks][2], a0.z, k0.z));
            cv.u[3] = f2b(__builtin_fmaf(qv2[ks][3], a0.w, k0.w));
            cv.u[4] = f2b(__builtin_fmaf(qv2[ks][4], a1.x, k1.x));
            cv.u[5] = f2b(__builtin_fmaf(qv2[ks][5], a1.y, k1.y));
            cv.u[6] = f2b(__builtin_fmaf(qv2[ks][6], a1.z, k1.z));
            cv.u[7] = f2b(__builtin_fmaf(qv2[ks][7], a1.w, k1.w));
            af[mt][ks] = cv.s;
        }
    }

    float l_run = 0.f;
    float oa0 = 0.f, oa1 = 0.f, oa2 = 0.f, oa3 = 0.f;
    const u16*   kbase = kb + bh * 65536;
    const float* vbase = vf + bh * 65536;
    const floatx4 z = (floatx4){0.f, 0.f, 0.f, 0.f};

    // prologue: load B-frags for j0 = 0
    short8 bf[2][2];
#pragma unroll
    for (int t = 0; t < 2; ++t)
#pragma unroll
        for (int ks = 0; ks < 2; ++ks) {
            uint4 kv = *(const uint4*)(kbase + (t * 16 + lo) * 64 + ks * 32 + hi * 8);
            bf[t][ks] = *(short8*)&kv;
        }

    for (int j0 = 0; j0 < 1024; j0 += 32) {
        floatx4 acc[4][2];
#pragma unroll
        for (int mt = 0; mt < 4; ++mt)
#pragma unroll
            for (int t = 0; t < 2; ++t)
                acc[mt][t] = __builtin_amdgcn_mfma_f32_16x16x32_bf16(af[mt][0], bf[t][0], z, 0, 0, 0);
#pragma unroll
        for (int mt = 0; mt < 4; ++mt)
#pragma unroll
            for (int t = 0; t < 2; ++t)
                acc[mt][t] = __builtin_amdgcn_mfma_f32_16x16x32_bf16(af[mt][1], bf[t][1], acc[mt][t], 0, 0, 0);

        // reload bf IN PLACE for the next iteration (last use was above);
        // the score+PV work below covers the ~200cy L2 latency.
        int jn = (j0 + 32) & 1023;                 // last reload wraps, unused
#pragma unroll
        for (int t = 0; t < 2; ++t)
#pragma unroll
            for (int ks = 0; ks < 2; ++ks) {
                uint4 kv = *(const uint4*)(kbase + (jn + t * 16 + lo) * 64 + ks * 32 + hi * 8);
                bf[t][ks] = *(short8*)&kv;
            }

        // score[j]: sigmoid-gelu (HW exp2) + pair-merged rcp; split chains
        float s0a = 0.f, s0b = 0.f, s1a = 0.f, s1b = 0.f;
#pragma unroll
        for (int mt = 0; mt < 4; ++mt)
#pragma unroll
            for (int r = 0; r < 4; ++r) {
                u32 pk = qw2[mt][r];
                float qp = u2f(pk & 0xFFFF0000u);
                float wc = u2f(pk << 16);
                float x0 = acc[mt][0][r] + qp;
                float x1 = acc[mt][1][r] + qp;
                float e0 = __builtin_amdgcn_exp2f(x0 * -2.45546696f);
                float e1 = __builtin_amdgcn_exp2f(x1 * -2.45546696f);
                float a0 = 1.0f + e0;
                float a1 = 1.0f + e1;
                float rc = __builtin_amdgcn_rcpf(a0 * a1);
                if (r & 1) {
                    s0a = __builtin_fmaf(x0 * wc, rc * a1, s0a);
                    s1a = __builtin_fmaf(x1 * wc, rc * a0, s1a);
                } else {
                    s0b = __builtin_fmaf(x0 * wc, rc * a1, s0b);
                    s1b = __builtin_fmaf(x1 * wc, rc * a0, s1b);
                }
            }
        float s0 = s0a + s0b, s1 = s1a + s1b;
        s0 += __shfl_xor(s0, 16); s0 += __shfl_xor(s0, 32);   // s[j=lo]
        s1 += __shfl_xor(s1, 16); s1 += __shfl_xor(s1, 32);   // s[j=16+lo]

        // fixed-shift softmax numerator (scores bounded |s|<~110, safe)
        float p0 = __builtin_amdgcn_exp2f(s0 - 16.0f);
        float p1 = __builtin_amdgcn_exp2f(s1 - 16.0f);
        l_run += p0 + p1;                          // per-lane partial (over lo)

        // PV: p[j=lane&15] lives in p0/p1 -> v_readlane broadcast, SGPR fma
        const float* vrow = vbase + j0 * 64 + lane;
#pragma unroll
        for (int j = 0; j < 16; j += 4) {
            float pa0 = rdlane(p0, j + 0), pb0 = rdlane(p1, j + 0);
            float pa1 = rdlane(p0, j + 1), pb1 = rdlane(p1, j + 1);
            float pa2 = rdlane(p0, j + 2), pb2 = rdlane(p1, j + 2);
            float pa3 = rdlane(p0, j + 3), pb3 = rdlane(p1, j + 3);
            oa0 = __builtin_fmaf(pa0, vrow[(j + 0) * 64], oa0);
            oa1 = __builtin_fmaf(pa1, vrow[(j + 1) * 64], oa1);
            oa2 = __builtin_fmaf(pa2, vrow[(j + 2) * 64], oa2);
            oa3 = __builtin_fmaf(pa3, vrow[(j + 3) * 64], oa3);
            oa0 = __builtin_fmaf(pb0, vrow[(j + 16) * 64], oa0);
            oa1 = __builtin_fmaf(pb1, vrow[(j + 17) * 64], oa1);
            oa2 = __builtin_fmaf(pb2, vrow[(j + 18) * 64], oa2);
            oa3 = __builtin_fmaf(pb3, vrow[(j + 19) * 64], oa3);
        }
    }

    float l = l_run;
    l += __shfl_xor(l, 1); l += __shfl_xor(l, 2);
    l += __shfl_xor(l, 4); l += __shfl_xor(l, 8);
    float outv = (oa0 + oa1 + oa2 + oa3) * __builtin_amdgcn_rcpf(l);
    int b = bh >> 3, h = bh & 7;
    ao[(b * 1024 + qi) * 512 + h * 64 + lane] = outv;   // (B,C,D) fp32
}

// ---------------------------------------------------------------------------
extern "C" void kernel_launch(void* const* d_in, const int* in_sizes, int n_in,
                              void* d_out, int out_size, void* d_ws, size_t ws_size,
                              hipStream_t stream)
{
    (void)in_sizes; (void)n_in; (void)out_size; (void)ws_size;
    const float* x  = (const float*)d_in[0];
    const float* Wq = (const float*)d_in[1];
    const float* bq = (const float*)d_in[2];
    const float* Wk = (const float*)d_in[3];
    const float* bk = (const float*)d_in[4];
    const float* Wv = (const float*)d_in[5];
    const float* bv = (const float*)d_in[6];
    const float* w1 = (const float*)d_in[7];
    const float* b1 = (const float*)d_in[8];
    const float* w2 = (const float*)d_in[9];
    // d_in[10] = b2: scalar shift of all scores -> softmax-invariant -> unused
    const float* Wo = (const float*)d_in[11];
    const float* bo = (const float*)d_in[12];

    char* ws = (char*)d_ws;
    float* q_ws = (float*)(ws);               // 4 MB fp32 (b,h,c,d)
    u16*   k_ws = (u16*)(ws + (4u << 20));    // 2 MB bf16 (b,h,c,d)
    float* v_ws = (float*)(ws + (6u << 20));  // 4 MB fp32 (b,h,c,d)
    float* a_ws = (float*)(ws + (10u << 20)); // 4 MB fp32 (b,c,D)

    dim3 blk(256);
    hipLaunchKernelGGL(gemm_qkv, dim3(32, 24), blk, 0, stream,
                       x, Wq, Wk, Wv, bq, bk, bv, q_ws, k_ws, v_ws);
    hipLaunchKernelGGL(attn10, dim3(4096), blk, 0, stream, q_ws, k_ws, v_ws, w1, b1, w2, a_ws);
    hipLaunchKernelGGL(gemm_out, dim3(32, 8), blk, 0, stream, a_ws, Wo, bo, (float*)d_out);
}

// Round 15
// 574.915 us; speedup vs baseline: 1.1689x; 1.0008x over previous
//
#include <hip/hip_runtime.h>
#include <cstdint>

typedef unsigned short u16;
typedef unsigned int u32;
typedef __attribute__((ext_vector_type(8))) short short8;   // 8 bf16 (MFMA A/B frag)
typedef __attribute__((ext_vector_type(4))) float floatx4;  // MFMA C/D frag

__device__ __forceinline__ float b2f(u16 u) {
    union { unsigned int i; float f; } c; c.i = ((unsigned int)u) << 16; return c.f;
}
__device__ __forceinline__ u16 f2b(float f) {
    union { float f; unsigned int i; } c; c.f = f;
    unsigned int u = c.i;
    u = u + 0x7FFFu + ((u >> 16) & 1u);   // RNE
    return (u16)(u >> 16);
}
__device__ __forceinline__ float rdlane(float v, int l) {
    union { float f; int i; } c; c.f = v;
    union { int i; float f; } o; o.i = __builtin_amdgcn_readlane(c.i, l);
    return o.f;
}
__device__ __forceinline__ float u2f(u32 u) { union { u32 u; float f; } c; c.u = u; return c.f; }

// ---------------------------------------------------------------------------
// Fused Q/K/V projection GEMM. Y[m,n] = sum_k x[m,k]*W[n,k] + bias[n].
// grid (32, 24): which = blockIdx.y>>3 (0=q fp32, 1=k bf16, 2=v fp32).
// ---------------------------------------------------------------------------
__global__ __launch_bounds__(256) void gemm_qkv(
    const float* __restrict__ x,
    const float* __restrict__ Wq, const float* __restrict__ Wk, const float* __restrict__ Wv,
    const float* __restrict__ bq, const float* __restrict__ bk, const float* __restrict__ bv,
    float* __restrict__ qout, u16* __restrict__ kout, float* __restrict__ vout)
{
    __shared__ u16 xs[64 * 72];
    __shared__ u16 wsl[64 * 72];
    int tid = threadIdx.x;
    int lane = tid & 63;
    int wv = tid >> 6;
    int lo = lane & 15, hi = lane >> 4;
    int which = blockIdx.y >> 3;
    int m0 = blockIdx.x * 64, n0 = (blockIdx.y & 7) * 64;
    const float* W    = which == 0 ? Wq : (which == 1 ? Wk : Wv);
    const float* bias = which == 0 ? bq : (which == 1 ? bk : bv);

    floatx4 acc[4];
#pragma unroll
    for (int mt = 0; mt < 4; ++mt) acc[mt] = (floatx4){0.f, 0.f, 0.f, 0.f};

    for (int k0 = 0; k0 < 512; k0 += 64) {
        __syncthreads();
#pragma unroll
        for (int i = 0; i < 2; ++i) {
            int v = tid + i * 256;
            int row = v >> 3, c8 = (v & 7) * 8;
            const float* ap = x + (m0 + row) * 512 + k0 + c8;
            const float* wp = W + (n0 + row) * 512 + k0 + c8;
            float4 a0 = *(const float4*)(ap);
            float4 a1 = *(const float4*)(ap + 4);
            float4 w0 = *(const float4*)(wp);
            float4 w1v = *(const float4*)(wp + 4);
            union { u16 u[8]; uint4 q; } ca, cw;
            ca.u[0] = f2b(a0.x); ca.u[1] = f2b(a0.y); ca.u[2] = f2b(a0.z); ca.u[3] = f2b(a0.w);
            ca.u[4] = f2b(a1.x); ca.u[5] = f2b(a1.y); ca.u[6] = f2b(a1.z); ca.u[7] = f2b(a1.w);
            cw.u[0] = f2b(w0.x); cw.u[1] = f2b(w0.y); cw.u[2] = f2b(w0.z); cw.u[3] = f2b(w0.w);
            cw.u[4] = f2b(w1v.x); cw.u[5] = f2b(w1v.y); cw.u[6] = f2b(w1v.z); cw.u[7] = f2b(w1v.w);
            *(uint4*)(xs + row * 72 + c8)  = ca.q;
            *(uint4*)(wsl + row * 72 + c8) = cw.q;
        }
        __syncthreads();
#pragma unroll
        for (int ks = 0; ks < 2; ++ks) {
            short8 bfr = *(const short8*)(wsl + (wv * 16 + lo) * 72 + ks * 32 + hi * 8);
#pragma unroll
            for (int mt = 0; mt < 4; ++mt) {
                short8 afr = *(const short8*)(xs + (mt * 16 + lo) * 72 + ks * 32 + hi * 8);
                acc[mt] = __builtin_amdgcn_mfma_f32_16x16x32_bf16(afr, bfr, acc[mt], 0, 0, 0);
            }
        }
    }

    int n = n0 + wv * 16 + lo;
    float bv2 = bias[n];
    int h = n >> 6, dd = n & 63;
#pragma unroll
    for (int mt = 0; mt < 4; ++mt) {
#pragma unroll
        for (int r = 0; r < 4; ++r) {
            int m = m0 + mt * 16 + hi * 4 + r;      // C/D: row=(lane>>4)*4+reg, col=lane&15
            float y = acc[mt][r] + bv2;
            int b = m >> 10, c = m & 1023;
            int idx = (((b * 8 + h) * 1024) + c) * 64 + dd;
            if (which == 0)      qout[idx] = y;
            else if (which == 1) kout[idx] = f2b(y);
            else                 vout[idx] = y;
        }
    }
}

// ---------------------------------------------------------------------------
// Output GEMM: Y[m,n] = sum_k A[m,k]*Wo[n,k] + bo[n], fp32 out, [m*512+n].
// ---------------------------------------------------------------------------
__global__ __launch_bounds__(256) void gemm_out(
    const float* __restrict__ A, const float* __restrict__ W, const float* __restrict__ bias,
    float* __restrict__ outf)
{
    __shared__ u16 xs[64 * 72];
    __shared__ u16 wsl[64 * 72];
    int tid = threadIdx.x;
    int lane = tid & 63;
    int wv = tid >> 6;
    int lo = lane & 15, hi = lane >> 4;
    int m0 = blockIdx.x * 64, n0 = blockIdx.y * 64;

    floatx4 acc[4];
#pragma unroll
    for (int mt = 0; mt < 4; ++mt) acc[mt] = (floatx4){0.f, 0.f, 0.f, 0.f};

    for (int k0 = 0; k0 < 512; k0 += 64) {
        __syncthreads();
#pragma unroll
        for (int i = 0; i < 2; ++i) {
            int v = tid + i * 256;
            int row = v >> 3, c8 = (v & 7) * 8;
            const float* ap = A + (m0 + row) * 512 + k0 + c8;
            const float* wp = W + (n0 + row) * 512 + k0 + c8;
            float4 a0 = *(const float4*)(ap);
            float4 a1 = *(const float4*)(ap + 4);
            float4 w0 = *(const float4*)(wp);
            float4 w1v = *(const float4*)(wp + 4);
            union { u16 u[8]; uint4 q; } ca, cw;
            ca.u[0] = f2b(a0.x); ca.u[1] = f2b(a0.y); ca.u[2] = f2b(a0.z); ca.u[3] = f2b(a0.w);
            ca.u[4] = f2b(a1.x); ca.u[5] = f2b(a1.y); ca.u[6] = f2b(a1.z); ca.u[7] = f2b(a1.w);
            cw.u[0] = f2b(w0.x); cw.u[1] = f2b(w0.y); cw.u[2] = f2b(w0.z); cw.u[3] = f2b(w0.w);
            cw.u[4] = f2b(w1v.x); cw.u[5] = f2b(w1v.y); cw.u[6] = f2b(w1v.z); cw.u[7] = f2b(w1v.w);
            *(uint4*)(xs + row * 72 + c8)  = ca.q;
            *(uint4*)(wsl + row * 72 + c8) = cw.q;
        }
        __syncthreads();
#pragma unroll
        for (int ks = 0; ks < 2; ++ks) {
            short8 bfr = *(const short8*)(wsl + (wv * 16 + lo) * 72 + ks * 32 + hi * 8);
#pragma unroll
            for (int mt = 0; mt < 4; ++mt) {
                short8 afr = *(const short8*)(xs + (mt * 16 + lo) * 72 + ks * 32 + hi * 8);
                acc[mt] = __builtin_amdgcn_mfma_f32_16x16x32_bf16(afr, bfr, acc[mt], 0, 0, 0);
            }
        }
    }

    int n = n0 + wv * 16 + lo;
    float bv = bias[n];
#pragma unroll
    for (int mt = 0; mt < 4; ++mt)
#pragma unroll
        for (int r = 0; r < 4; ++r) {
            int m = m0 + mt * 16 + hi * 4 + r;
            outf[m * 512 + n] = acc[mt][r] + bv;
        }
}

// ---------------------------------------------------------------------------
// Fused second-order attention, v11 = v10 + two algebraic op-cuts:
//  * exp2-arg fold: af and qp pre-scaled by c = -2.45546696 (=-1.702*log2e),
//    1/c folded into w2c -> hid arrives as x' = c*x, exp2(x') is direct
//    (the per-eval mul is gone); x*wc == x' * (wc/c).
//  * 4-way merged reciprocal: rc = rcp(a0*a1*a2*a3); sigma_i recovered from
//    partial products (9 VALU + 1 trans per 4 evals vs 6 + 2).
//    Safe: |hid| <~ 10 -> a <= 2^25 -> 4-product <= 2^100 < 2^128.
// ---------------------------------------------------------------------------
__global__ __launch_bounds__(256, 4) void attn11(
    const float* __restrict__ qf, const u16* __restrict__ kb, const float* __restrict__ vf,
    const float* __restrict__ w1, const float* __restrict__ b1, const float* __restrict__ w2,
    float* __restrict__ ao)
{
    __shared__ float q_l[4 * 64];
    int tid = threadIdx.x;
    int lane = tid & 63;
    int wv = tid >> 6;
    int lo = lane & 15, hi = lane >> 4;
    int bh = blockIdx.x >> 8;                      // 0..15 = b*8+h
    int qi = ((blockIdx.x & 255) << 2) | wv;       // query 0..1023

    const float NA = -2.45546696f;                 // -1.702 * log2(e)

    q_l[wv * 64 + lane] = qf[(bh * 1024 + qi) * 64 + lane];

    // qp[e]+b1[e] at lane=e
    float qpacc = b1[lane];
#pragma unroll
    for (int d8 = 0; d8 < 64; d8 += 8) {
        float4 wa = *(const float4*)(w1 + lane * 192 + d8);
        float4 wb = *(const float4*)(w1 + lane * 192 + d8 + 4);
        const float* q8 = q_l + wv * 64 + d8;      // wave-uniform broadcast reads
        qpacc = __builtin_fmaf(q8[0], wa.x, qpacc);
        qpacc = __builtin_fmaf(q8[1], wa.y, qpacc);
        qpacc = __builtin_fmaf(q8[2], wa.z, qpacc);
        qpacc = __builtin_fmaf(q8[3], wa.w, qpacc);
        qpacc = __builtin_fmaf(q8[4], wb.x, qpacc);
        qpacc = __builtin_fmaf(q8[5], wb.y, qpacc);
        qpacc = __builtin_fmaf(q8[6], wb.z, qpacc);
        qpacc = __builtin_fmaf(q8[7], wb.w, qpacc);
    }
    qpacc *= NA;                                   // qp' = c * (qp + b1)

    // packed (qp' | wc') at C/D-row indexing: e = mt*16 + hi*4 + r
    // wc' = w2[e] * (1/8)*log2e * (1/c) = w2[e] * -0.07344288
    u32 qw2[4][4];
    float w2row = w2[lane] * -0.07344288f;
#pragma unroll
    for (int mt = 0; mt < 4; ++mt)
#pragma unroll
        for (int r = 0; r < 4; ++r) {
            int e = mt * 16 + hi * 4 + r;
            u32 qp_b = (u32)f2b(__shfl(qpacc, e));
            u32 wc_b = (u32)f2b(__shfl(w2row, e));
            qw2[mt][r] = (qp_b << 16) | wc_b;
        }

    // q pieces for frag build: qv2[ks][j] = q[ks*32 + hi*8 + j]
    float qv2[2][8];
#pragma unroll
    for (int ks = 0; ks < 2; ++ks)
#pragma unroll
        for (int j = 0; j < 8; ++j)
            qv2[ks][j] = q_l[wv * 64 + ks * 32 + hi * 8 + j];

    // A-frags: c * qw'[e = mt*16+lo][dd = ks*32 + hi*8 + j], bf16
    short8 af[4][2];
#pragma unroll
    for (int mt = 0; mt < 4; ++mt) {
        const float* wr = w1 + (mt * 16 + lo) * 192;
#pragma unroll
        for (int ks = 0; ks < 2; ++ks) {
            int dd0 = ks * 32 + hi * 8;
            float4 a0 = *(const float4*)(wr + 128 + dd0);
            float4 a1 = *(const float4*)(wr + 128 + dd0 + 4);
            float4 k0 = *(const float4*)(wr + 64 + dd0);
            float4 k1 = *(const float4*)(wr + 64 + dd0 + 4);
            union { u16 u[8]; short8 s; } cv;
            cv.u[0] = f2b(NA * __builtin_fmaf(qv2[ks][0], a0.x, k0.x));
            cv.u[1] = f2b(NA * __builtin_fmaf(qv2[ks][1], a0.y, k0.y));
            cv.u[2] = f2b(NA * __builtin_fmaf(qv2[ks][2], a0.z, k0.z));
            cv.u[3] = f2b(NA * __builtin_fmaf(qv2[ks][3], a0.w, k0.w));
            cv.u[4] = f2b(NA * __builtin_fmaf(qv2[ks][4], a1.x, k1.x));
            cv.u[5] = f2b(NA * __builtin_fmaf(qv2[ks][5], a1.y, k1.y));
            cv.u[6] = f2b(NA * __builtin_fmaf(qv2[ks][6], a1.z, k1.z));
            cv.u[7] = f2b(NA * __builtin_fmaf(qv2[ks][7], a1.w, k1.w));
            af[mt][ks] = cv.s;
        }
    }

    float l_run = 0.f;
    float oa0 = 0.f, oa1 = 0.f, oa2 = 0.f, oa3 = 0.f;
    const u16*   kbase = kb + bh * 65536;
    const float* vbase = vf + bh * 65536;
    const floatx4 z = (floatx4){0.f, 0.f, 0.f, 0.f};

    // prologue: load B-frags for j0 = 0
    short8 bf[2][2];
#pragma unroll
    for (int t = 0; t < 2; ++t)
#pragma unroll
        for (int ks = 0; ks < 2; ++ks) {
            uint4 kv = *(const uint4*)(kbase + (t * 16 + lo) * 64 + ks * 32 + hi * 8);
            bf[t][ks] = *(short8*)&kv;
        }

    for (int j0 = 0; j0 < 1024; j0 += 32) {
        floatx4 acc[4][2];
#pragma unroll
        for (int mt = 0; mt < 4; ++mt)
#pragma unroll
            for (int t = 0; t < 2; ++t)
                acc[mt][t] = __builtin_amdgcn_mfma_f32_16x16x32_bf16(af[mt][0], bf[t][0], z, 0, 0, 0);
#pragma unroll
        for (int mt = 0; mt < 4; ++mt)
#pragma unroll
            for (int t = 0; t < 2; ++t)
                acc[mt][t] = __builtin_amdgcn_mfma_f32_16x16x32_bf16(af[mt][1], bf[t][1], acc[mt][t], 0, 0, 0);

        // reload bf IN PLACE for the next iteration (last use was above);
        // score+PV below covers the ~200cy L2 latency.
        int jn = (j0 + 32) & 1023;                 // last reload wraps, unused
#pragma unroll
        for (int t = 0; t < 2; ++t)
#pragma unroll
            for (int ks = 0; ks < 2; ++ks) {
                uint4 kv = *(const uint4*)(kbase + (jn + t * 16 + lo) * 64 + ks * 32 + hi * 8);
                bf[t][ks] = *(short8*)&kv;
            }

        // score: x' = acc + qp'; e = exp2(x'); sigma via 4-way merged rcp
        float s0a = 0.f, s0b = 0.f, s1a = 0.f, s1b = 0.f;
#pragma unroll
        for (int mt = 0; mt < 4; ++mt)
#pragma unroll
            for (int t = 0; t < 2; ++t) {
                float x0, x1, x2, x3, w0, w1v, w2v, w3;
                {
                    u32 pk0 = qw2[mt][0], pk1 = qw2[mt][1];
                    u32 pk2 = qw2[mt][2], pk3 = qw2[mt][3];
                    x0 = acc[mt][t][0] + u2f(pk0 & 0xFFFF0000u);
                    x1 = acc[mt][t][1] + u2f(pk1 & 0xFFFF0000u);
                    x2 = acc[mt][t][2] + u2f(pk2 & 0xFFFF0000u);
                    x3 = acc[mt][t][3] + u2f(pk3 & 0xFFFF0000u);
                    w0 = u2f(pk0 << 16); w1v = u2f(pk1 << 16);
                    w2v = u2f(pk2 << 16); w3 = u2f(pk3 << 16);
                }
                float a0 = 1.0f + __builtin_amdgcn_exp2f(x0);
                float a1 = 1.0f + __builtin_amdgcn_exp2f(x1);
                float a2 = 1.0f + __builtin_amdgcn_exp2f(x2);
                float a3 = 1.0f + __builtin_amdgcn_exp2f(x3);
                float ab = a0 * a1, cd = a2 * a3;
                float rc = __builtin_amdgcn_rcpf(ab * cd);
                float rcab = rc * ab, rccd = rc * cd;
                if (t == 0) {
                    s0a = __builtin_fmaf(x0 * w0,  rccd * a1, s0a);
                    s0b = __builtin_fmaf(x1 * w1v, rccd * a0, s0b);
                    s0a = __builtin_fmaf(x2 * w2v, rcab * a3, s0a);
                    s0b = __builtin_fmaf(x3 * w3,  rcab * a2, s0b);
                } else {
                    s1a = __builtin_fmaf(x0 * w0,  rccd * a1, s1a);
                    s1b = __builtin_fmaf(x1 * w1v, rccd * a0, s1b);
                    s1a = __builtin_fmaf(x2 * w2v, rcab * a3, s1a);
                    s1b = __builtin_fmaf(x3 * w3,  rcab * a2, s1b);
                }
            }
        float s0 = s0a + s0b, s1 = s1a + s1b;
        s0 += __shfl_xor(s0, 16); s0 += __shfl_xor(s0, 32);   // s[j=lo]
        s1 += __shfl_xor(s1, 16); s1 += __shfl_xor(s1, 32);   // s[j=16+lo]

        // fixed-shift softmax numerator (scores bounded, safe)
        float p0 = __builtin_amdgcn_exp2f(s0 - 16.0f);
        float p1 = __builtin_amdgcn_exp2f(s1 - 16.0f);
        l_run += p0 + p1;                          // per-lane partial (over lo)

        // PV: p[j=lane&15] lives in p0/p1 -> v_readlane broadcast, SGPR fma
        const float* vrow = vbase + j0 * 64 + lane;
#pragma unroll
        for (int j = 0; j < 16; j += 4) {
            float pa0 = rdlane(p0, j + 0), pb0 = rdlane(p1, j + 0);
            float pa1 = rdlane(p0, j + 1), pb1 = rdlane(p1, j + 1);
            float pa2 = rdlane(p0, j + 2), pb2 = rdlane(p1, j + 2);
            float pa3 = rdlane(p0, j + 3), pb3 = rdlane(p1, j + 3);
            oa0 = __builtin_fmaf(pa0, vrow[(j + 0) * 64], oa0);
            oa1 = __builtin_fmaf(pa1, vrow[(j + 1) * 64], oa1);
            oa2 = __builtin_fmaf(pa2, vrow[(j + 2) * 64], oa2);
            oa3 = __builtin_fmaf(pa3, vrow[(j + 3) * 64], oa3);
            oa0 = __builtin_fmaf(pb0, vrow[(j + 16) * 64], oa0);
            oa1 = __builtin_fmaf(pb1, vrow[(j + 17) * 64], oa1);
            oa2 = __builtin_fmaf(pb2, vrow[(j + 18) * 64], oa2);
            oa3 = __builtin_fmaf(pb3, vrow[(j + 19) * 64], oa3);
        }
    }

    float l = l_run;
    l += __shfl_xor(l, 1); l += __shfl_xor(l, 2);
    l += __shfl_xor(l, 4); l += __shfl_xor(l, 8);
    float outv = (oa0 + oa1 + oa2 + oa3) * __builtin_amdgcn_rcpf(l);
    int b = bh >> 3, h = bh & 7;
    ao[(b * 1024 + qi) * 512 + h * 64 + lane] = outv;   // (B,C,D) fp32
}

// ---------------------------------------------------------------------------
extern "C" void kernel_launch(void* const* d_in, const int* in_sizes, int n_in,
                              void* d_out, int out_size, void* d_ws, size_t ws_size,
                              hipStream_t stream)
{
    (void)in_sizes; (void)n_in; (void)out_size; (void)ws_size;
    const float* x  = (const float*)d_in[0];
    const float* Wq = (const float*)d_in[1];
    const float* bq = (const float*)d_in[2];
    const float* Wk = (const float*)d_in[3];
    const float* bk = (const float*)d_in[4];
    const float* Wv = (const float*)d_in[5];
    const float* bv = (const float*)d_in[6];
    const float* w1 = (const float*)d_in[7];
    const float* b1 = (const float*)d_in[8];
    const float* w2 = (const float*)d_in[9];
    // d_in[10] = b2: scalar shift of all scores -> softmax-invariant -> unused
    const float* Wo = (const float*)d_in[11];
    const float* bo = (const float*)d_in[12];

    char* ws = (char*)d_ws;
    float* q_ws = (float*)(ws);               // 4 MB fp32 (b,h,c,d)
    u16*   k_ws = (u16*)(ws + (4u << 20));    // 2 MB bf16 (b,h,c,d)
    float* v_ws = (float*)(ws + (6u << 20));  // 4 MB fp32 (b,h,c,d)
    float* a_ws = (float*)(ws + (10u << 20)); // 4 MB fp32 (b,c,D)

    dim3 blk(256);
    hipLaunchKernelGGL(gemm_qkv, dim3(32, 24), blk, 0, stream,
                       x, Wq, Wk, Wv, bq, bk, bv, q_ws, k_ws, v_ws);
    hipLaunchKernelGGL(attn11, dim3(4096), blk, 0, stream, q_ws, k_ws, v_ws, w1, b1, w2, a_ws);
    hipLaunchKernelGGL(gemm_out, dim3(32, 8), blk, 0, stream, a_ws, Wo, bo, (float*)d_out);
}

// Round 16
// 554.064 us; speedup vs baseline: 1.2129x; 1.0376x over previous
//
#include <hip/hip_runtime.h>
#include <cstdint>

typedef unsigned short u16;
typedef unsigned int u32;
typedef __attribute__((ext_vector_type(8))) short short8;   // 8 bf16 (MFMA A/B frag)
typedef __attribute__((ext_vector_type(4))) float floatx4;  // MFMA C/D frag

__device__ __forceinline__ float b2f(u16 u) {
    union { unsigned int i; float f; } c; c.i = ((unsigned int)u) << 16; return c.f;
}
__device__ __forceinline__ u16 f2b(float f) {
    union { float f; unsigned int i; } c; c.f = f;
    unsigned int u = c.i;
    u = u + 0x7FFFu + ((u >> 16) & 1u);   // RNE
    return (u16)(u >> 16);
}
__device__ __forceinline__ float rdlane(float v, int l) {
    union { float f; int i; } c; c.f = v;
    union { int i; float f; } o; o.i = __builtin_amdgcn_readlane(c.i, l);
    return o.f;
}
__device__ __forceinline__ float u2f(u32 u) { union { u32 u; float f; } c; c.u = u; return c.f; }

// ---------------------------------------------------------------------------
// Fused Q/K/V projection GEMM. Y[m,n] = sum_k x[m,k]*W[n,k] + bias[n].
// grid (32, 24): which = blockIdx.y>>3 (0=q fp32, 1=k bf16, 2=v fp32).
// ---------------------------------------------------------------------------
__global__ __launch_bounds__(256) void gemm_qkv(
    const float* __restrict__ x,
    const float* __restrict__ Wq, const float* __restrict__ Wk, const float* __restrict__ Wv,
    const float* __restrict__ bq, const float* __restrict__ bk, const float* __restrict__ bv,
    float* __restrict__ qout, u16* __restrict__ kout, float* __restrict__ vout)
{
    __shared__ u16 xs[64 * 72];
    __shared__ u16 wsl[64 * 72];
    int tid = threadIdx.x;
    int lane = tid & 63;
    int wv = tid >> 6;
    int lo = lane & 15, hi = lane >> 4;
    int which = blockIdx.y >> 3;
    int m0 = blockIdx.x * 64, n0 = (blockIdx.y & 7) * 64;
    const float* W    = which == 0 ? Wq : (which == 1 ? Wk : Wv);
    const float* bias = which == 0 ? bq : (which == 1 ? bk : bv);

    floatx4 acc[4];
#pragma unroll
    for (int mt = 0; mt < 4; ++mt) acc[mt] = (floatx4){0.f, 0.f, 0.f, 0.f};

    for (int k0 = 0; k0 < 512; k0 += 64) {
        __syncthreads();
#pragma unroll
        for (int i = 0; i < 2; ++i) {
            int v = tid + i * 256;
            int row = v >> 3, c8 = (v & 7) * 8;
            const float* ap = x + (m0 + row) * 512 + k0 + c8;
            const float* wp = W + (n0 + row) * 512 + k0 + c8;
            float4 a0 = *(const float4*)(ap);
            float4 a1 = *(const float4*)(ap + 4);
            float4 w0 = *(const float4*)(wp);
            float4 w1v = *(const float4*)(wp + 4);
            union { u16 u[8]; uint4 q; } ca, cw;
            ca.u[0] = f2b(a0.x); ca.u[1] = f2b(a0.y); ca.u[2] = f2b(a0.z); ca.u[3] = f2b(a0.w);
            ca.u[4] = f2b(a1.x); ca.u[5] = f2b(a1.y); ca.u[6] = f2b(a1.z); ca.u[7] = f2b(a1.w);
            cw.u[0] = f2b(w0.x); cw.u[1] = f2b(w0.y); cw.u[2] = f2b(w0.z); cw.u[3] = f2b(w0.w);
            cw.u[4] = f2b(w1v.x); cw.u[5] = f2b(w1v.y); cw.u[6] = f2b(w1v.z); cw.u[7] = f2b(w1v.w);
            *(uint4*)(xs + row * 72 + c8)  = ca.q;
            *(uint4*)(wsl + row * 72 + c8) = cw.q;
        }
        __syncthreads();
#pragma unroll
        for (int ks = 0; ks < 2; ++ks) {
            short8 bfr = *(const short8*)(wsl + (wv * 16 + lo) * 72 + ks * 32 + hi * 8);
#pragma unroll
            for (int mt = 0; mt < 4; ++mt) {
                short8 afr = *(const short8*)(xs + (mt * 16 + lo) * 72 + ks * 32 + hi * 8);
                acc[mt] = __builtin_amdgcn_mfma_f32_16x16x32_bf16(afr, bfr, acc[mt], 0, 0, 0);
            }
        }
    }

    int n = n0 + wv * 16 + lo;
    float bv2 = bias[n];
    int h = n >> 6, dd = n & 63;
#pragma unroll
    for (int mt = 0; mt < 4; ++mt) {
#pragma unroll
        for (int r = 0; r < 4; ++r) {
            int m = m0 + mt * 16 + hi * 4 + r;      // C/D: row=(lane>>4)*4+reg, col=lane&15
            float y = acc[mt][r] + bv2;
            int b = m >> 10, c = m & 1023;
            int idx = (((b * 8 + h) * 1024) + c) * 64 + dd;
            if (which == 0)      qout[idx] = y;
            else if (which == 1) kout[idx] = f2b(y);
            else                 vout[idx] = y;
        }
    }
}

// ---------------------------------------------------------------------------
// Output GEMM: Y[m,n] = sum_k A[m,k]*Wo[n,k] + bo[n], fp32 out, [m*512+n].
// ---------------------------------------------------------------------------
__global__ __launch_bounds__(256) void gemm_out(
    const float* __restrict__ A, const float* __restrict__ W, const float* __restrict__ bias,
    float* __restrict__ outf)
{
    __shared__ u16 xs[64 * 72];
    __shared__ u16 wsl[64 * 72];
    int tid = threadIdx.x;
    int lane = tid & 63;
    int wv = tid >> 6;
    int lo = lane & 15, hi = lane >> 4;
    int m0 = blockIdx.x * 64, n0 = blockIdx.y * 64;

    floatx4 acc[4];
#pragma unroll
    for (int mt = 0; mt < 4; ++mt) acc[mt] = (floatx4){0.f, 0.f, 0.f, 0.f};

    for (int k0 = 0; k0 < 512; k0 += 64) {
        __syncthreads();
#pragma unroll
        for (int i = 0; i < 2; ++i) {
            int v = tid + i * 256;
            int row = v >> 3, c8 = (v & 7) * 8;
            const float* ap = A + (m0 + row) * 512 + k0 + c8;
            const float* wp = W + (n0 + row) * 512 + k0 + c8;
            float4 a0 = *(const float4*)(ap);
            float4 a1 = *(const float4*)(ap + 4);
            float4 w0 = *(const float4*)(wp);
            float4 w1v = *(const float4*)(wp + 4);
            union { u16 u[8]; uint4 q; } ca, cw;
            ca.u[0] = f2b(a0.x); ca.u[1] = f2b(a0.y); ca.u[2] = f2b(a0.z); ca.u[3] = f2b(a0.w);
            ca.u[4] = f2b(a1.x); ca.u[5] = f2b(a1.y); ca.u[6] = f2b(a1.z); ca.u[7] = f2b(a1.w);
            cw.u[0] = f2b(w0.x); cw.u[1] = f2b(w0.y); cw.u[2] = f2b(w0.z); cw.u[3] = f2b(w0.w);
            cw.u[4] = f2b(w1v.x); cw.u[5] = f2b(w1v.y); cw.u[6] = f2b(w1v.z); cw.u[7] = f2b(w1v.w);
            *(uint4*)(xs + row * 72 + c8)  = ca.q;
            *(uint4*)(wsl + row * 72 + c8) = cw.q;
        }
        __syncthreads();
#pragma unroll
        for (int ks = 0; ks < 2; ++ks) {
            short8 bfr = *(const short8*)(wsl + (wv * 16 + lo) * 72 + ks * 32 + hi * 8);
#pragma unroll
            for (int mt = 0; mt < 4; ++mt) {
                short8 afr = *(const short8*)(xs + (mt * 16 + lo) * 72 + ks * 32 + hi * 8);
                acc[mt] = __builtin_amdgcn_mfma_f32_16x16x32_bf16(afr, bfr, acc[mt], 0, 0, 0);
            }
        }
    }

    int n = n0 + wv * 16 + lo;
    float bv = bias[n];
#pragma unroll
    for (int mt = 0; mt < 4; ++mt)
#pragma unroll
        for (int r = 0; r < 4; ++r) {
            int m = m0 + mt * 16 + hi * 4 + r;
            outf[m * 512 + n] = acc[mt][r] + bv;
        }
}

// ---------------------------------------------------------------------------
// Fused second-order attention, v12 = R14 base + exp2-arg fold (R15, good)
// + rank-1 qp fold hoisted OUT of the loop:
//  * af and qp' pre-scaled by c = -1.702*log2e; w2 scaled by 1/c; acc IS
//    the exp2 argument directly (no per-eval mul, no per-eval qp add).
//  * qpinit[mt] = mfma(af4[mt], bf4, 0) computed ONCE (rank-1 trick,
//    HW-validated R11); reused as loop-invariant C-init every iteration:
//    -64 adds -16 unpacks -32 muls per iter, zero extra per-iter MFMA.
//  * w2c as 8 packed-bf16 u32 (+16 cheap unpacks/iter).
//  * pair-merged rcp (R14's clean variant), in-place bf reload, readlane PV,
//    fixed-shift softmax.
// ---------------------------------------------------------------------------
__global__ __launch_bounds__(256, 4) void attn12(
    const float* __restrict__ qf, const u16* __restrict__ kb, const float* __restrict__ vf,
    const float* __restrict__ w1, const float* __restrict__ b1, const float* __restrict__ w2,
    float* __restrict__ ao)
{
    __shared__ float q_l[4 * 64];
    int tid = threadIdx.x;
    int lane = tid & 63;
    int wv = tid >> 6;
    int lo = lane & 15, hi = lane >> 4;
    int bh = blockIdx.x >> 8;                      // 0..15 = b*8+h
    int qi = ((blockIdx.x & 255) << 2) | wv;       // query 0..1023

    const float NA = -2.45546696f;                 // -1.702 * log2(e)

    q_l[wv * 64 + lane] = qf[(bh * 1024 + qi) * 64 + lane];

    // qp[e]+b1[e] at lane=e
    float qpacc = b1[lane];
#pragma unroll
    for (int d8 = 0; d8 < 64; d8 += 8) {
        float4 wa = *(const float4*)(w1 + lane * 192 + d8);
        float4 wb = *(const float4*)(w1 + lane * 192 + d8 + 4);
        const float* q8 = q_l + wv * 64 + d8;      // wave-uniform broadcast reads
        qpacc = __builtin_fmaf(q8[0], wa.x, qpacc);
        qpacc = __builtin_fmaf(q8[1], wa.y, qpacc);
        qpacc = __builtin_fmaf(q8[2], wa.z, qpacc);
        qpacc = __builtin_fmaf(q8[3], wa.w, qpacc);
        qpacc = __builtin_fmaf(q8[4], wb.x, qpacc);
        qpacc = __builtin_fmaf(q8[5], wb.y, qpacc);
        qpacc = __builtin_fmaf(q8[6], wb.z, qpacc);
        qpacc = __builtin_fmaf(q8[7], wb.w, qpacc);
    }
    qpacc *= NA;                                   // qp' = c * (qp + b1)

    // w2c packed: wc' = w2[e] * (1/8)*log2e / c = w2[e] * -0.07344288
    // pairs (r,r+1) at e = mt*16 + hi*4 + r
    u32 wcp[4][2];
    float w2row = w2[lane] * -0.07344288f;
#pragma unroll
    for (int mt = 0; mt < 4; ++mt)
#pragma unroll
        for (int h2 = 0; h2 < 2; ++h2) {
            int e0 = mt * 16 + hi * 4 + h2 * 2;
            u32 lo16 = (u32)f2b(__shfl(w2row, e0));
            u32 hi16 = (u32)f2b(__shfl(w2row, e0 + 1));
            wcp[mt][h2] = (hi16 << 16) | lo16;
        }

    // q pieces for frag build: qv2[ks][j] = q[ks*32 + hi*8 + j]
    float qv2[2][8];
#pragma unroll
    for (int ks = 0; ks < 2; ++ks)
#pragma unroll
        for (int j = 0; j < 8; ++j)
            qv2[ks][j] = q_l[wv * 64 + ks * 32 + hi * 8 + j];

    // A-frags: c * qw'[e = mt*16+lo][dd = ks*32 + hi*8 + j], bf16
    short8 af[4][2];
#pragma unroll
    for (int mt = 0; mt < 4; ++mt) {
        const float* wr = w1 + (mt * 16 + lo) * 192;
#pragma unroll
        for (int ks = 0; ks < 2; ++ks) {
            int dd0 = ks * 32 + hi * 8;
            float4 a0 = *(const float4*)(wr + 128 + dd0);
            float4 a1 = *(const float4*)(wr + 128 + dd0 + 4);
            float4 k0 = *(const float4*)(wr + 64 + dd0);
            float4 k1 = *(const float4*)(wr + 64 + dd0 + 4);
            union { u16 u[8]; short8 s; } cv;
            cv.u[0] = f2b(NA * __builtin_fmaf(qv2[ks][0], a0.x, k0.x));
            cv.u[1] = f2b(NA * __builtin_fmaf(qv2[ks][1], a0.y, k0.y));
            cv.u[2] = f2b(NA * __builtin_fmaf(qv2[ks][2], a0.z, k0.z));
            cv.u[3] = f2b(NA * __builtin_fmaf(qv2[ks][3], a0.w, k0.w));
            cv.u[4] = f2b(NA * __builtin_fmaf(qv2[ks][4], a1.x, k1.x));
            cv.u[5] = f2b(NA * __builtin_fmaf(qv2[ks][5], a1.y, k1.y));
            cv.u[6] = f2b(NA * __builtin_fmaf(qv2[ks][6], a1.z, k1.z));
            cv.u[7] = f2b(NA * __builtin_fmaf(qv2[ks][7], a1.w, k1.w));
            af[mt][ks] = cv.s;
        }
    }

    // rank-1 qp' C-init, loop-invariant: qpinit[mt][n] = qp'[e=mt*16+m] for
    // all n. A[m][k]=qp' at k=0; B[n][k]=1 at k=0. (validated R11)
    floatx4 qpinit[4];
    {
        const floatx4 z = (floatx4){0.f, 0.f, 0.f, 0.f};
        union { u16 u[8]; short8 s; } bb;
#pragma unroll
        for (int i = 0; i < 8; ++i) bb.u[i] = 0;
        bb.u[0] = (hi == 0) ? (u16)0x3F80 : (u16)0;   // bf16 1.0 at k=0
#pragma unroll
        for (int mt = 0; mt < 4; ++mt) {
            float qpv = __shfl(qpacc, mt * 16 + lo);
            union { u16 u[8]; short8 s; } aa;
#pragma unroll
            for (int i = 0; i < 8; ++i) aa.u[i] = 0;
            aa.u[0] = (hi == 0) ? f2b(qpv) : (u16)0;
            qpinit[mt] = __builtin_amdgcn_mfma_f32_16x16x32_bf16(aa.s, bb.s, z, 0, 0, 0);
        }
    }

    float l_run = 0.f;
    float oa0 = 0.f, oa1 = 0.f, oa2 = 0.f, oa3 = 0.f;
    const u16*   kbase = kb + bh * 65536;
    const float* vbase = vf + bh * 65536;

    // prologue: load B-frags for j0 = 0
    short8 bf[2][2];
#pragma unroll
    for (int t = 0; t < 2; ++t)
#pragma unroll
        for (int ks = 0; ks < 2; ++ks) {
            uint4 kv = *(const uint4*)(kbase + (t * 16 + lo) * 64 + ks * 32 + hi * 8);
            bf[t][ks] = *(short8*)&kv;
        }

    for (int j0 = 0; j0 < 1024; j0 += 32) {
        floatx4 acc[4][2];
#pragma unroll
        for (int mt = 0; mt < 4; ++mt)
#pragma unroll
            for (int t = 0; t < 2; ++t)
                acc[mt][t] = __builtin_amdgcn_mfma_f32_16x16x32_bf16(af[mt][0], bf[t][0], qpinit[mt], 0, 0, 0);
#pragma unroll
        for (int mt = 0; mt < 4; ++mt)
#pragma unroll
            for (int t = 0; t < 2; ++t)
                acc[mt][t] = __builtin_amdgcn_mfma_f32_16x16x32_bf16(af[mt][1], bf[t][1], acc[mt][t], 0, 0, 0);

        // reload bf IN PLACE for the next iteration (last use was above);
        // score+PV below covers the ~200cy L2 latency.
        int jn = (j0 + 32) & 1023;                 // last reload wraps, unused
#pragma unroll
        for (int t = 0; t < 2; ++t)
#pragma unroll
            for (int ks = 0; ks < 2; ++ks) {
                uint4 kv = *(const uint4*)(kbase + (jn + t * 16 + lo) * 64 + ks * 32 + hi * 8);
                bf[t][ks] = *(short8*)&kv;
            }

        // score: acc IS x' = c*hid; e = exp2(x'); sigma via pair-merged rcp
        float s0a = 0.f, s0b = 0.f, s1a = 0.f, s1b = 0.f;
#pragma unroll
        for (int mt = 0; mt < 4; ++mt)
#pragma unroll
            for (int h2 = 0; h2 < 2; ++h2) {
                u32 wp = wcp[mt][h2];
                float w0 = u2f(wp << 16);
                float w1v = u2f(wp & 0xFFFF0000u);
#pragma unroll
                for (int t = 0; t < 2; ++t) {
                    float x0 = acc[mt][t][h2 * 2 + 0];
                    float x1 = acc[mt][t][h2 * 2 + 1];
                    float a0 = 1.0f + __builtin_amdgcn_exp2f(x0);
                    float a1 = 1.0f + __builtin_amdgcn_exp2f(x1);
                    float rc = __builtin_amdgcn_rcpf(a0 * a1);
                    if (t == 0) {
                        s0a = __builtin_fmaf(x0 * w0,  rc * a1, s0a);
                        s0b = __builtin_fmaf(x1 * w1v, rc * a0, s0b);
                    } else {
                        s1a = __builtin_fmaf(x0 * w0,  rc * a1, s1a);
                        s1b = __builtin_fmaf(x1 * w1v, rc * a0, s1b);
                    }
                }
            }
        float s0 = s0a + s0b, s1 = s1a + s1b;
        s0 += __shfl_xor(s0, 16); s0 += __shfl_xor(s0, 32);   // s[j=lo]
        s1 += __shfl_xor(s1, 16); s1 += __shfl_xor(s1, 32);   // s[j=16+lo]

        // fixed-shift softmax numerator (scores bounded, safe)
        float p0 = __builtin_amdgcn_exp2f(s0 - 16.0f);
        float p1 = __builtin_amdgcn_exp2f(s1 - 16.0f);
        l_run += p0 + p1;                          // per-lane partial (over lo)

        // PV: p[j=lane&15] lives in p0/p1 -> v_readlane broadcast, SGPR fma
        const float* vrow = vbase + j0 * 64 + lane;
#pragma unroll
        for (int j = 0; j < 16; j += 4) {
            float pa0 = rdlane(p0, j + 0), pb0 = rdlane(p1, j + 0);
            float pa1 = rdlane(p0, j + 1), pb1 = rdlane(p1, j + 1);
            float pa2 = rdlane(p0, j + 2), pb2 = rdlane(p1, j + 2);
            float pa3 = rdlane(p0, j + 3), pb3 = rdlane(p1, j + 3);
            oa0 = __builtin_fmaf(pa0, vrow[(j + 0) * 64], oa0);
            oa1 = __builtin_fmaf(pa1, vrow[(j + 1) * 64], oa1);
            oa2 = __builtin_fmaf(pa2, vrow[(j + 2) * 64], oa2);
            oa3 = __builtin_fmaf(pa3, vrow[(j + 3) * 64], oa3);
            oa0 = __builtin_fmaf(pb0, vrow[(j + 16) * 64], oa0);
            oa1 = __builtin_fmaf(pb1, vrow[(j + 17) * 64], oa1);
            oa2 = __builtin_fmaf(pb2, vrow[(j + 18) * 64], oa2);
            oa3 = __builtin_fmaf(pb3, vrow[(j + 19) * 64], oa3);
        }
    }

    float l = l_run;
    l += __shfl_xor(l, 1); l += __shfl_xor(l, 2);
    l += __shfl_xor(l, 4); l += __shfl_xor(l, 8);
    float outv = (oa0 + oa1 + oa2 + oa3) * __builtin_amdgcn_rcpf(l);
    int b = bh >> 3, h = bh & 7;
    ao[(b * 1024 + qi) * 512 + h * 64 + lane] = outv;   // (B,C,D) fp32
}

// ---------------------------------------------------------------------------
extern "C" void kernel_launch(void* const* d_in, const int* in_sizes, int n_in,
                              void* d_out, int out_size, void* d_ws, size_t ws_size,
                              hipStream_t stream)
{
    (void)in_sizes; (void)n_in; (void)out_size; (void)ws_size;
    const float* x  = (const float*)d_in[0];
    const float* Wq = (const float*)d_in[1];
    const float* bq = (const float*)d_in[2];
    const float* Wk = (const float*)d_in[3];
    const float* bk = (const float*)d_in[4];
    const float* Wv = (const float*)d_in[5];
    const float* bv = (const float*)d_in[6];
    const float* w1 = (const float*)d_in[7];
    const float* b1 = (const float*)d_in[8];
    const float* w2 = (const float*)d_in[9];
    // d_in[10] = b2: scalar shift of all scores -> softmax-invariant -> unused
    const float* Wo = (const float*)d_in[11];
    const float* bo = (const float*)d_in[12];

    char* ws = (char*)d_ws;
    float* q_ws = (float*)(ws);               // 4 MB fp32 (b,h,c,d)
    u16*   k_ws = (u16*)(ws + (4u << 20));    // 2 MB bf16 (b,h,c,d)
    float* v_ws = (float*)(ws + (6u << 20));  // 4 MB fp32 (b,h,c,d)
    float* a_ws = (float*)(ws + (10u << 20)); // 4 MB fp32 (b,c,D)

    dim3 blk(256);
    hipLaunchKernelGGL(gemm_qkv, dim3(32, 24), blk, 0, stream,
                       x, Wq, Wk, Wv, bq, bk, bv, q_ws, k_ws, v_ws);
    hipLaunchKernelGGL(attn12, dim3(4096), blk, 0, stream, q_ws, k_ws, v_ws, w1, b1, w2, a_ws);
    hipLaunchKernelGGL(gemm_out, dim3(32, 8), blk, 0, stream, a_ws, Wo, bo, (float*)d_out);
}

// Round 17
// 553.462 us; speedup vs baseline: 1.2142x; 1.0011x over previous
//
#include <hip/hip_runtime.h>
#include <cstdint>

typedef unsigned short u16;
typedef unsigned int u32;
typedef __attribute__((ext_vector_type(8))) short short8;   // 8 bf16 (MFMA A/B frag)
typedef __attribute__((ext_vector_type(4))) float floatx4;  // MFMA C/D frag

__device__ __forceinline__ float b2f(u16 u) {
    union { unsigned int i; float f; } c; c.i = ((unsigned int)u) << 16; return c.f;
}
__device__ __forceinline__ u16 f2b(float f) {
    union { float f; unsigned int i; } c; c.f = f;
    unsigned int u = c.i;
    u = u + 0x7FFFu + ((u >> 16) & 1u);   // RNE
    return (u16)(u >> 16);
}
__device__ __forceinline__ float rdlane(float v, int l) {
    union { float f; int i; } c; c.f = v;
    union { int i; float f; } o; o.i = __builtin_amdgcn_readlane(c.i, l);
    return o.f;
}
__device__ __forceinline__ float u2f(u32 u) { union { u32 u; float f; } c; c.u = u; return c.f; }

// ---------------------------------------------------------------------------
// Fused Q/K/V projection GEMM. Y[m,n] = sum_k x[m,k]*W[n,k] + bias[n].
// grid (32, 24): which = blockIdx.y>>3 (0=q fp32, 1=k bf16, 2=v fp32).
// ---------------------------------------------------------------------------
__global__ __launch_bounds__(256) void gemm_qkv(
    const float* __restrict__ x,
    const float* __restrict__ Wq, const float* __restrict__ Wk, const float* __restrict__ Wv,
    const float* __restrict__ bq, const float* __restrict__ bk, const float* __restrict__ bv,
    float* __restrict__ qout, u16* __restrict__ kout, float* __restrict__ vout)
{
    __shared__ u16 xs[64 * 72];
    __shared__ u16 wsl[64 * 72];
    int tid = threadIdx.x;
    int lane = tid & 63;
    int wv = tid >> 6;
    int lo = lane & 15, hi = lane >> 4;
    int which = blockIdx.y >> 3;
    int m0 = blockIdx.x * 64, n0 = (blockIdx.y & 7) * 64;
    const float* W    = which == 0 ? Wq : (which == 1 ? Wk : Wv);
    const float* bias = which == 0 ? bq : (which == 1 ? bk : bv);

    floatx4 acc[4];
#pragma unroll
    for (int mt = 0; mt < 4; ++mt) acc[mt] = (floatx4){0.f, 0.f, 0.f, 0.f};

    for (int k0 = 0; k0 < 512; k0 += 64) {
        __syncthreads();
#pragma unroll
        for (int i = 0; i < 2; ++i) {
            int v = tid + i * 256;
            int row = v >> 3, c8 = (v & 7) * 8;
            const float* ap = x + (m0 + row) * 512 + k0 + c8;
            const float* wp = W + (n0 + row) * 512 + k0 + c8;
            float4 a0 = *(const float4*)(ap);
            float4 a1 = *(const float4*)(ap + 4);
            float4 w0 = *(const float4*)(wp);
            float4 w1v = *(const float4*)(wp + 4);
            union { u16 u[8]; uint4 q; } ca, cw;
            ca.u[0] = f2b(a0.x); ca.u[1] = f2b(a0.y); ca.u[2] = f2b(a0.z); ca.u[3] = f2b(a0.w);
            ca.u[4] = f2b(a1.x); ca.u[5] = f2b(a1.y); ca.u[6] = f2b(a1.z); ca.u[7] = f2b(a1.w);
            cw.u[0] = f2b(w0.x); cw.u[1] = f2b(w0.y); cw.u[2] = f2b(w0.z); cw.u[3] = f2b(w0.w);
            cw.u[4] = f2b(w1v.x); cw.u[5] = f2b(w1v.y); cw.u[6] = f2b(w1v.z); cw.u[7] = f2b(w1v.w);
            *(uint4*)(xs + row * 72 + c8)  = ca.q;
            *(uint4*)(wsl + row * 72 + c8) = cw.q;
        }
        __syncthreads();
#pragma unroll
        for (int ks = 0; ks < 2; ++ks) {
            short8 bfr = *(const short8*)(wsl + (wv * 16 + lo) * 72 + ks * 32 + hi * 8);
#pragma unroll
            for (int mt = 0; mt < 4; ++mt) {
                short8 afr = *(const short8*)(xs + (mt * 16 + lo) * 72 + ks * 32 + hi * 8);
                acc[mt] = __builtin_amdgcn_mfma_f32_16x16x32_bf16(afr, bfr, acc[mt], 0, 0, 0);
            }
        }
    }

    int n = n0 + wv * 16 + lo;
    float bv2 = bias[n];
    int h = n >> 6, dd = n & 63;
#pragma unroll
    for (int mt = 0; mt < 4; ++mt) {
#pragma unroll
        for (int r = 0; r < 4; ++r) {
            int m = m0 + mt * 16 + hi * 4 + r;      // C/D: row=(lane>>4)*4+reg, col=lane&15
            float y = acc[mt][r] + bv2;
            int b = m >> 10, c = m & 1023;
            int idx = (((b * 8 + h) * 1024) + c) * 64 + dd;
            if (which == 0)      qout[idx] = y;
            else if (which == 1) kout[idx] = f2b(y);
            else                 vout[idx] = y;
        }
    }
}

// ---------------------------------------------------------------------------
// Output GEMM: Y[m,n] = sum_k A[m,k]*Wo[n,k] + bo[n], fp32 out, [m*512+n].
// ---------------------------------------------------------------------------
__global__ __launch_bounds__(256) void gemm_out(
    const float* __restrict__ A, const float* __restrict__ W, const float* __restrict__ bias,
    float* __restrict__ outf)
{
    __shared__ u16 xs[64 * 72];
    __shared__ u16 wsl[64 * 72];
    int tid = threadIdx.x;
    int lane = tid & 63;
    int wv = tid >> 6;
    int lo = lane & 15, hi = lane >> 4;
    int m0 = blockIdx.x * 64, n0 = blockIdx.y * 64;

    floatx4 acc[4];
#pragma unroll
    for (int mt = 0; mt < 4; ++mt) acc[mt] = (floatx4){0.f, 0.f, 0.f, 0.f};

    for (int k0 = 0; k0 < 512; k0 += 64) {
        __syncthreads();
#pragma unroll
        for (int i = 0; i < 2; ++i) {
            int v = tid + i * 256;
            int row = v >> 3, c8 = (v & 7) * 8;
            const float* ap = A + (m0 + row) * 512 + k0 + c8;
            const float* wp = W + (n0 + row) * 512 + k0 + c8;
            float4 a0 = *(const float4*)(ap);
            float4 a1 = *(const float4*)(ap + 4);
            float4 w0 = *(const float4*)(wp);
            float4 w1v = *(const float4*)(wp + 4);
            union { u16 u[8]; uint4 q; } ca, cw;
            ca.u[0] = f2b(a0.x); ca.u[1] = f2b(a0.y); ca.u[2] = f2b(a0.z); ca.u[3] = f2b(a0.w);
            ca.u[4] = f2b(a1.x); ca.u[5] = f2b(a1.y); ca.u[6] = f2b(a1.z); ca.u[7] = f2b(a1.w);
            cw.u[0] = f2b(w0.x); cw.u[1] = f2b(w0.y); cw.u[2] = f2b(w0.z); cw.u[3] = f2b(w0.w);
            cw.u[4] = f2b(w1v.x); cw.u[5] = f2b(w1v.y); cw.u[6] = f2b(w1v.z); cw.u[7] = f2b(w1v.w);
            *(uint4*)(xs + row * 72 + c8)  = ca.q;
            *(uint4*)(wsl + row * 72 + c8) = cw.q;
        }
        __syncthreads();
#pragma unroll
        for (int ks = 0; ks < 2; ++ks) {
            short8 bfr = *(const short8*)(wsl + (wv * 16 + lo) * 72 + ks * 32 + hi * 8);
#pragma unroll
            for (int mt = 0; mt < 4; ++mt) {
                short8 afr = *(const short8*)(xs + (mt * 16 + lo) * 72 + ks * 32 + hi * 8);
                acc[mt] = __builtin_amdgcn_mfma_f32_16x16x32_bf16(afr, bfr, acc[mt], 0, 0, 0);
            }
        }
    }

    int n = n0 + wv * 16 + lo;
    float bv = bias[n];
#pragma unroll
    for (int mt = 0; mt < 4; ++mt)
#pragma unroll
        for (int r = 0; r < 4; ++r) {
            int m = m0 + mt * 16 + hi * 4 + r;
            outf[m * 512 + n] = acc[mt][r] + bv;
        }
}

// ---------------------------------------------------------------------------
// Fused second-order attention, v13 = v12 with the MFMA->score consumption
// software-pipelined per mt-tile to cut live accumulators 32->16 regs:
// AGPR = af 32 + qpinit 16 + acc 16 = 64 exact; arch side ~52 < 64
// -> 4 waves/SIMD with NO scratch spills (v12 had 44MB spill traffic).
// Loop body: issue mt+1's 4 MFMAs, score mt's pair (hides MFMA latency),
// rotate. bf in-place reload sits in the mt=3 slot (after last bf use).
// ---------------------------------------------------------------------------
__global__ __launch_bounds__(256, 4) void attn13(
    const float* __restrict__ qf, const u16* __restrict__ kb, const float* __restrict__ vf,
    const float* __restrict__ w1, const float* __restrict__ b1, const float* __restrict__ w2,
    float* __restrict__ ao)
{
    __shared__ float q_l[4 * 64];
    int tid = threadIdx.x;
    int lane = tid & 63;
    int wv = tid >> 6;
    int lo = lane & 15, hi = lane >> 4;
    int bh = blockIdx.x >> 8;                      // 0..15 = b*8+h
    int qi = ((blockIdx.x & 255) << 2) | wv;       // query 0..1023

    const float NA = -2.45546696f;                 // -1.702 * log2(e)

    q_l[wv * 64 + lane] = qf[(bh * 1024 + qi) * 64 + lane];

    // qp[e]+b1[e] at lane=e
    float qpacc = b1[lane];
#pragma unroll
    for (int d8 = 0; d8 < 64; d8 += 8) {
        float4 wa = *(const float4*)(w1 + lane * 192 + d8);
        float4 wb = *(const float4*)(w1 + lane * 192 + d8 + 4);
        const float* q8 = q_l + wv * 64 + d8;      // wave-uniform broadcast reads
        qpacc = __builtin_fmaf(q8[0], wa.x, qpacc);
        qpacc = __builtin_fmaf(q8[1], wa.y, qpacc);
        qpacc = __builtin_fmaf(q8[2], wa.z, qpacc);
        qpacc = __builtin_fmaf(q8[3], wa.w, qpacc);
        qpacc = __builtin_fmaf(q8[4], wb.x, qpacc);
        qpacc = __builtin_fmaf(q8[5], wb.y, qpacc);
        qpacc = __builtin_fmaf(q8[6], wb.z, qpacc);
        qpacc = __builtin_fmaf(q8[7], wb.w, qpacc);
    }
    qpacc *= NA;                                   // qp' = c * (qp + b1)

    // w2c packed: wc' = w2[e] * (1/8)*log2e / c = w2[e] * -0.07344288
    // pairs (r,r+1) at e = mt*16 + hi*4 + r
    u32 wcp[4][2];
    float w2row = w2[lane] * -0.07344288f;
#pragma unroll
    for (int mt = 0; mt < 4; ++mt)
#pragma unroll
        for (int h2 = 0; h2 < 2; ++h2) {
            int e0 = mt * 16 + hi * 4 + h2 * 2;
            u32 lo16 = (u32)f2b(__shfl(w2row, e0));
            u32 hi16 = (u32)f2b(__shfl(w2row, e0 + 1));
            wcp[mt][h2] = (hi16 << 16) | lo16;
        }

    // q pieces for frag build: qv2[ks][j] = q[ks*32 + hi*8 + j]
    float qv2[2][8];
#pragma unroll
    for (int ks = 0; ks < 2; ++ks)
#pragma unroll
        for (int j = 0; j < 8; ++j)
            qv2[ks][j] = q_l[wv * 64 + ks * 32 + hi * 8 + j];

    // A-frags: c * qw'[e = mt*16+lo][dd = ks*32 + hi*8 + j], bf16
    short8 af[4][2];
#pragma unroll
    for (int mt = 0; mt < 4; ++mt) {
        const float* wr = w1 + (mt * 16 + lo) * 192;
#pragma unroll
        for (int ks = 0; ks < 2; ++ks) {
            int dd0 = ks * 32 + hi * 8;
            float4 a0 = *(const float4*)(wr + 128 + dd0);
            float4 a1 = *(const float4*)(wr + 128 + dd0 + 4);
            float4 k0 = *(const float4*)(wr + 64 + dd0);
            float4 k1 = *(const float4*)(wr + 64 + dd0 + 4);
            union { u16 u[8]; short8 s; } cv;
            cv.u[0] = f2b(NA * __builtin_fmaf(qv2[ks][0], a0.x, k0.x));
            cv.u[1] = f2b(NA * __builtin_fmaf(qv2[ks][1], a0.y, k0.y));
            cv.u[2] = f2b(NA * __builtin_fmaf(qv2[ks][2], a0.z, k0.z));
            cv.u[3] = f2b(NA * __builtin_fmaf(qv2[ks][3], a0.w, k0.w));
            cv.u[4] = f2b(NA * __builtin_fmaf(qv2[ks][4], a1.x, k1.x));
            cv.u[5] = f2b(NA * __builtin_fmaf(qv2[ks][5], a1.y, k1.y));
            cv.u[6] = f2b(NA * __builtin_fmaf(qv2[ks][6], a1.z, k1.z));
            cv.u[7] = f2b(NA * __builtin_fmaf(qv2[ks][7], a1.w, k1.w));
            af[mt][ks] = cv.s;
        }
    }

    // rank-1 qp' C-init, loop-invariant (HW-validated R11/R16)
    floatx4 qpinit[4];
    {
        const floatx4 z = (floatx4){0.f, 0.f, 0.f, 0.f};
        union { u16 u[8]; short8 s; } bb;
#pragma unroll
        for (int i = 0; i < 8; ++i) bb.u[i] = 0;
        bb.u[0] = (hi == 0) ? (u16)0x3F80 : (u16)0;   // bf16 1.0 at k=0
#pragma unroll
        for (int mt = 0; mt < 4; ++mt) {
            float qpv = __shfl(qpacc, mt * 16 + lo);
            union { u16 u[8]; short8 s; } aa;
#pragma unroll
            for (int i = 0; i < 8; ++i) aa.u[i] = 0;
            aa.u[0] = (hi == 0) ? f2b(qpv) : (u16)0;
            qpinit[mt] = __builtin_amdgcn_mfma_f32_16x16x32_bf16(aa.s, bb.s, z, 0, 0, 0);
        }
    }

    float l_run = 0.f;
    float oa0 = 0.f, oa1 = 0.f, oa2 = 0.f, oa3 = 0.f;
    const u16*   kbase = kb + bh * 65536;
    const float* vbase = vf + bh * 65536;

    // prologue: load B-frags for j0 = 0
    short8 bf[2][2];
#pragma unroll
    for (int t = 0; t < 2; ++t)
#pragma unroll
        for (int ks = 0; ks < 2; ++ks) {
            uint4 kv = *(const uint4*)(kbase + (t * 16 + lo) * 64 + ks * 32 + hi * 8);
            bf[t][ks] = *(short8*)&kv;
        }

    for (int j0 = 0; j0 < 1024; j0 += 32) {
        float s0a = 0.f, s0b = 0.f, s1a = 0.f, s1b = 0.f;

        // pipeline prologue: mt=0's 4 MFMAs
        floatx4 aP[2], aN[2];
        aP[0] = __builtin_amdgcn_mfma_f32_16x16x32_bf16(af[0][0], bf[0][0], qpinit[0], 0, 0, 0);
        aP[0] = __builtin_amdgcn_mfma_f32_16x16x32_bf16(af[0][1], bf[0][1], aP[0], 0, 0, 0);
        aP[1] = __builtin_amdgcn_mfma_f32_16x16x32_bf16(af[0][0], bf[1][0], qpinit[0], 0, 0, 0);
        aP[1] = __builtin_amdgcn_mfma_f32_16x16x32_bf16(af[0][1], bf[1][1], aP[1], 0, 0, 0);

#pragma unroll
        for (int mt = 0; mt < 4; ++mt) {
            if (mt < 3) {
                // issue mt+1's MFMAs; their latency is hidden by scoring mt below
                aN[0] = __builtin_amdgcn_mfma_f32_16x16x32_bf16(af[mt + 1][0], bf[0][0], qpinit[mt + 1], 0, 0, 0);
                aN[0] = __builtin_amdgcn_mfma_f32_16x16x32_bf16(af[mt + 1][1], bf[0][1], aN[0], 0, 0, 0);
                aN[1] = __builtin_amdgcn_mfma_f32_16x16x32_bf16(af[mt + 1][0], bf[1][0], qpinit[mt + 1], 0, 0, 0);
                aN[1] = __builtin_amdgcn_mfma_f32_16x16x32_bf16(af[mt + 1][1], bf[1][1], aN[1], 0, 0, 0);
            } else {
                // last bf use was mt=3's MFMAs (issued in mt=2 slot) -> reload
                // in place for next j0; score tail + PV covers L2 latency.
                int jn = (j0 + 32) & 1023;         // last reload wraps, unused
#pragma unroll
                for (int t = 0; t < 2; ++t)
#pragma unroll
                    for (int ks = 0; ks < 2; ++ks) {
                        uint4 kv = *(const uint4*)(kbase + (jn + t * 16 + lo) * 64 + ks * 32 + hi * 8);
                        bf[t][ks] = *(short8*)&kv;
                    }
            }

            // score mt's pair: acc IS x' = c*hid; sigma via pair-merged rcp
#pragma unroll
            for (int h2 = 0; h2 < 2; ++h2) {
                u32 wp = wcp[mt][h2];
                float w0 = u2f(wp << 16);
                float w1v = u2f(wp & 0xFFFF0000u);
#pragma unroll
                for (int t = 0; t < 2; ++t) {
                    float x0 = aP[t][h2 * 2 + 0];
                    float x1 = aP[t][h2 * 2 + 1];
                    float a0 = 1.0f + __builtin_amdgcn_exp2f(x0);
                    float a1 = 1.0f + __builtin_amdgcn_exp2f(x1);
                    float rc = __builtin_amdgcn_rcpf(a0 * a1);
                    if (t == 0) {
                        s0a = __builtin_fmaf(x0 * w0,  rc * a1, s0a);
                        s0b = __builtin_fmaf(x1 * w1v, rc * a0, s0b);
                    } else {
                        s1a = __builtin_fmaf(x0 * w0,  rc * a1, s1a);
                        s1b = __builtin_fmaf(x1 * w1v, rc * a0, s1b);
                    }
                }
            }
            aP[0] = aN[0];
            aP[1] = aN[1];
        }

        float s0 = s0a + s0b, s1 = s1a + s1b;
        s0 += __shfl_xor(s0, 16); s0 += __shfl_xor(s0, 32);   // s[j=lo]
        s1 += __shfl_xor(s1, 16); s1 += __shfl_xor(s1, 32);   // s[j=16+lo]

        // fixed-shift softmax numerator (scores bounded, safe)
        float p0 = __builtin_amdgcn_exp2f(s0 - 16.0f);
        float p1 = __builtin_amdgcn_exp2f(s1 - 16.0f);
        l_run += p0 + p1;                          // per-lane partial (over lo)

        // PV: p[j=lane&15] lives in p0/p1 -> v_readlane broadcast, SGPR fma
        const float* vrow = vbase + j0 * 64 + lane;
#pragma unroll
        for (int j = 0; j < 16; j += 4) {
            float pa0 = rdlane(p0, j + 0), pb0 = rdlane(p1, j + 0);
            float pa1 = rdlane(p0, j + 1), pb1 = rdlane(p1, j + 1);
            float pa2 = rdlane(p0, j + 2), pb2 = rdlane(p1, j + 2);
            float pa3 = rdlane(p0, j + 3), pb3 = rdlane(p1, j + 3);
            oa0 = __builtin_fmaf(pa0, vrow[(j + 0) * 64], oa0);
            oa1 = __builtin_fmaf(pa1, vrow[(j + 1) * 64], oa1);
            oa2 = __builtin_fmaf(pa2, vrow[(j + 2) * 64], oa2);
            oa3 = __builtin_fmaf(pa3, vrow[(j + 3) * 64], oa3);
            oa0 = __builtin_fmaf(pb0, vrow[(j + 16) * 64], oa0);
            oa1 = __builtin_fmaf(pb1, vrow[(j + 17) * 64], oa1);
            oa2 = __builtin_fmaf(pb2, vrow[(j + 18) * 64], oa2);
            oa3 = __builtin_fmaf(pb3, vrow[(j + 19) * 64], oa3);
        }
    }

    float l = l_run;
    l += __shfl_xor(l, 1); l += __shfl_xor(l, 2);
    l += __shfl_xor(l, 4); l += __shfl_xor(l, 8);
    float outv = (oa0 + oa1 + oa2 + oa3) * __builtin_amdgcn_rcpf(l);
    int b = bh >> 3, h = bh & 7;
    ao[(b * 1024 + qi) * 512 + h * 64 + lane] = outv;   // (B,C,D) fp32
}

// ---------------------------------------------------------------------------
extern "C" void kernel_launch(void* const* d_in, const int* in_sizes, int n_in,
                              void* d_out, int out_size, void* d_ws, size_t ws_size,
                              hipStream_t stream)
{
    (void)in_sizes; (void)n_in; (void)out_size; (void)ws_size;
    const float* x  = (const float*)d_in[0];
    const float* Wq = (const float*)d_in[1];
    const float* bq = (const float*)d_in[2];
    const float* Wk = (const float*)d_in[3];
    const float* bk = (const float*)d_in[4];
    const float* Wv = (const float*)d_in[5];
    const float* bv = (const float*)d_in[6];
    const float* w1 = (const float*)d_in[7];
    const float* b1 = (const float*)d_in[8];
    const float* w2 = (const float*)d_in[9];
    // d_in[10] = b2: scalar shift of all scores -> softmax-invariant -> unused
    const float* Wo = (const float*)d_in[11];
    const float* bo = (const float*)d_in[12];

    char* ws = (char*)d_ws;
    float* q_ws = (float*)(ws);               // 4 MB fp32 (b,h,c,d)
    u16*   k_ws = (u16*)(ws + (4u << 20));    // 2 MB bf16 (b,h,c,d)
    float* v_ws = (float*)(ws + (6u << 20));  // 4 MB fp32 (b,h,c,d)
    float* a_ws = (float*)(ws + (10u << 20)); // 4 MB fp32 (b,c,D)

    dim3 blk(256);
    hipLaunchKernelGGL(gemm_qkv, dim3(32, 24), blk, 0, stream,
                       x, Wq, Wk, Wv, bq, bk, bv, q_ws, k_ws, v_ws);
    hipLaunchKernelGGL(attn13, dim3(4096), blk, 0, stream, q_ws, k_ws, v_ws, w1, b1, w2, a_ws);
    hipLaunchKernelGGL(gemm_out, dim3(32, 8), blk, 0, stream, a_ws, Wo, bo, (float*)d_out);
}